// Round 3
// baseline (755.735 us; speedup 1.0000x reference)
//
#include <hip/hip_runtime.h>
#include <hip/hip_bf16.h>

typedef __hip_bfloat16 bf16;

#define N_ATOMS 10000
#define N_EDGES 200000
#define REC 84   // packed edge record, T units: [0:32) rb0, [32:56) rb1, [56:72) rb2,
                 // [72] sh0, [73:76) sh1, [76:81) sh2

// ======== float region of ws (float offsets) ========
#define SCG   0        // 615 cg coeffs f32
#define SINV  616      // 296 inv per channel (+pad)
#define SS1P  1024     // 296*64 partials
#define SS2P  19968    // 5*64 partials
#define SWS2  20288    // 5 (+pad)
#define SINTS 20352    // int region starts here (float idx)
// ======== int region (offsets in ints, relative to SINTS) ========
#define IFLAG  0
#define ICOUNT 16      // 10000
#define IOFFS  10016   // 10001 (+pad)
#define ICURS  20032   // 10000
#define IELIST 30032   // small: 200000 ints | stream: 400000 ints (int2)
#define INTS_END_BIG   430032
#define SEREC (SINTS + INTS_END_BIG)   // packed records start here (float idx)

// ---- d_out element offsets ----
#define O0 0
#define O1 320000
#define O2 1040000
#define OY 1840000
#define OUT_ELEMS 5200000

__device__ __forceinline__ float b2f(bf16 x){ return __bfloat162float(x); }
__device__ __forceinline__ bf16  f2b(float x){ return __float2bfloat16(x); }

__device__ __forceinline__ float ldv(const float* p, int i){ return p[i]; }
__device__ __forceinline__ float ldv(const bf16*  p, int i){ return b2f(p[i]); }
__device__ __forceinline__ void  stv(float* p, int i, float v){ p[i] = v; }
__device__ __forceinline__ void  stv(bf16*  p, int i, float v){ p[i] = f2b(v); }

template<typename T> __device__ __forceinline__ int dtid();
template<> __device__ __forceinline__ int dtid<bf16>(){ return 0; }
template<> __device__ __forceinline__ int dtid<float>(){ return 1; }

struct Ptrs15 { const void* p[15]; };
struct LinP   { const void* W[5]; const void* B[5]; };

__constant__ int c_cg_sizes[15] = {1,9,25,9,9,27,45,45,75,25,45,75,25,75,125};
__constant__ int c_fin[5]   = {72,80,40,72,32};
__constant__ int c_kout[5]  = {32,24,24,16,16};
__constant__ int c_yoff[5]  = {OY+0, OY+320000, OY+1040000, OY+1760000, OY+2560000};
__constant__ int c_numel[5] = {320000,720000,720000,800000,800000};
__constant__ int c_cum[6]   = {0,32,104,176,256,336};
__constant__ int c_xb[5]    = {0,72,312,432,792};
__constant__ int c_Ms[5]    = {1,3,3,5,5};

// ---------------- zero + dtype probe (fallback path) ----------------
__global__ void k_zero(float* wsf, int* wsi,
                       const unsigned short* rb0u, const unsigned short* embu) {
  if (blockIdx.x == 0 && threadIdx.x < 64) {
    int lane = threadIdx.x;
    int bad = 0;
    for (int i = lane; i < 256; i += 64) {
      unsigned u1 = ((unsigned)rb0u[2*i]) << 16;
      unsigned u2 = ((unsigned)embu[2*i]) << 16;
      float v1 = __uint_as_float(u1);
      float v2 = __uint_as_float(u2);
      if (!(fabsf(v1) < 1e9f) || !(fabsf(v2) < 1e9f)) bad = 1;
    }
    unsigned long long any = __ballot(bad);
    if (lane == 0) wsi[IFLAG] = (any != 0ULL) ? 1 : 0;   // 1 = fp32, 0 = bf16
  }
  int i = blockIdx.x*blockDim.x + threadIdx.x;
  if (i < N_ATOMS) wsi[ICOUNT + i] = 0;
  int j = i - N_ATOMS;
  if (j >= 0 && j < N_ATOMS) wsi[ICURS + j] = 0;
  j -= N_ATOMS;
  if (j >= 0 && j < 18944) wsf[SS1P + j] = 0.f;
  j -= 18944;
  if (j >= 0 && j < 325) wsf[SS2P + j] = 0.f;
}

template<typename T>
__global__ void k_cg(Ptrs15 cg, float* wsf, const int* flag) {
  if (flag[0] != dtid<T>()) return;
  int i = blockIdx.x*blockDim.x + threadIdx.x;
  if (i >= 615) return;
  int s = 0, off = i;
  while (off >= c_cg_sizes[s]) { off -= c_cg_sizes[s]; ++s; }
  wsf[SCG + i] = ldv((const T*)cg.p[s], off);
}

__global__ void k_hist(const int* __restrict__ centers, int* __restrict__ counts) {
  int e = blockIdx.x*blockDim.x + threadIdx.x;
  if (e < N_EDGES) atomicAdd(&counts[centers[e]], 1);
}

__global__ void k_scan(const int* __restrict__ counts, int* __restrict__ offs) {
  __shared__ int part[1024];
  int t = threadIdx.x;
  int base = t*10;
  int s = 0;
  for (int i = 0; i < 10; ++i) { int idx = base+i; if (idx < N_ATOMS) s += counts[idx]; }
  part[t] = s;
  __syncthreads();
  for (int d = 1; d < 1024; d <<= 1) {
    int v = part[t];
    int add = (t >= d) ? part[t-d] : 0;
    __syncthreads();
    part[t] = v + add;
    __syncthreads();
  }
  int run = (t == 0) ? 0 : part[t-1];
  for (int i = 0; i < 10; ++i) {
    int idx = base+i;
    if (idx < N_ATOMS) { offs[idx] = run; run += counts[idx]; }
  }
  if (t == 1023) offs[N_ATOMS] = part[1023];
}

// small-path scatter (flag-gated; cursors are single-use per launch)
template<typename T>
__global__ void k_scatterT(const int* __restrict__ centers, const int* __restrict__ offs,
                           int* __restrict__ cursors, int* __restrict__ elist,
                           const int* __restrict__ flag) {
  if (flag[0] != dtid<T>()) return;
  int e = blockIdx.x*blockDim.x + threadIdx.x;
  if (e < N_EDGES) {
    int c = centers[e];
    int p = atomicAdd(&cursors[c], 1);
    elist[offs[c] + p] = e;
  }
}

// ---------------- payload repack: sort edge data into center order ----------
// Half-wave (32 lanes) per edge. Reads coalesced (lane=channel, sequential e),
// writes one contiguous REC-record at the sorted position. Stores n in el2.
template<typename T>
__global__ __launch_bounds__(256) void k_pack(
    const T* __restrict__ rb0, const T* __restrict__ rb1, const T* __restrict__ rb2,
    const T* __restrict__ sh0, const T* __restrict__ sh1, const T* __restrict__ sh2,
    const int* __restrict__ centers, const int* __restrict__ neighbors,
    const int* __restrict__ offs, int* __restrict__ cursors,
    int2* __restrict__ el2, T* __restrict__ erec, const int* __restrict__ flag)
{
  if (flag[0] != dtid<T>()) return;
  int tid = blockIdx.x*blockDim.x + threadIdx.x;
  int half = tid >> 5;
  int k = tid & 31;
  int lane = threadIdx.x & 63;
  int nhalf = (gridDim.x*blockDim.x) >> 5;
  for (int e = half; e < N_EDGES; e += nhalf) {
    int pos = 0;
    if (k == 0) {
      int c = centers[e];
      pos = offs[c] + atomicAdd(&cursors[c], 1);
    }
    pos = __shfl(pos, lane & 32);
    T* r = erec + (size_t)pos * REC;
    r[k] = rb0[e*32 + k];
    if (k < 24) r[32+k] = rb1[e*24 + k];
    if (k < 16) r[56+k] = rb2[e*16 + k];
    if (k == 0) { r[72] = sh0[e]; el2[pos] = make_int2(e, neighbors[e]); }
    if (k >= 1 && k < 4) r[72+k] = sh1[e*3 + (k-1)];
    if (k >= 4 && k < 9) r[72+k] = sh2[e*5 + (k-4)];
  }
}

// ---------------- main K-loop: 4 waves specialized over the 15 CG pairs -----
// MODE 1: gathered (fallback), epilogue A (densities + s1p)
// MODE 2: gathered (fallback), epilogue B (normalize + linear + s2p)
// MODE 3: STREAMING from packed records, epilogue A
// MODE 4: STREAMING, epilogue B
// Streaming loop has NO __syncthreads: waves fully decoupled; edge data is a
// sequential read per atom. Only atom tables (emb/f0/f1/f2, 8.6MB) gathered.
template<typename T, int MODE>
__global__ __launch_bounds__(256) void k_main(
    const T* __restrict__ rb0, const T* __restrict__ rb1, const T* __restrict__ rb2,
    const T* __restrict__ sh0, const T* __restrict__ sh1, const T* __restrict__ sh2,
    const T* __restrict__ emb, const T* __restrict__ f0, const T* __restrict__ f1,
    const T* __restrict__ f2, const int* __restrict__ neighbors,
    const int* __restrict__ offs, const int* __restrict__ elist,
    const T* __restrict__ erec,
    const float* __restrict__ cgf, float* __restrict__ s1p,
    const float* __restrict__ inv, float* __restrict__ s2p,
    LinP lp, T* __restrict__ out, const int* __restrict__ flag)
{
  if (flag[0] != dtid<T>()) return;
  constexpr bool STRM = (MODE >= 3);
  constexpr int EPI = (MODE == 1 || MODE == 3) ? 1 : 2;
  int lane = threadIdx.x & 63;
  int wv   = threadIdx.x >> 6;
  int tix  = threadIdx.x;
  int k32 = lane & 31, e2 = lane >> 5;
  int k16 = lane & 15, e4 = lane >> 4;
  int k24 = (k32 < 24) ? k32 : 23;
  float m24 = (k32 < 24) ? 1.f : 0.f;
  const int2* el2 = (const int2*)elist;

  __shared__ int2 sel[256];
  __shared__ __align__(16) float L[952];
  __shared__ float red[4][5];

  int a0 = blockIdx.x * 4;
  for (int a = a0; a < a0 + 4; ++a) {
    int beg = offs[a];
    int cnt = offs[a+1] - beg;
    int ab = a & 63;

    float acc[25];
    #pragma unroll
    for (int i = 0; i < 25; ++i) acc[i] = 0.f;

    if constexpr (STRM) {
      const T* rbase = erec + (size_t)beg * REC;
      const int2* eb = el2 + beg;
      if (wv == 0) {
        // W0: lanes (e2,k32), 4 edges/iter; all loads batched before FMAs
        for (int base = 0; base < cnt; base += 4) {
          int i0 = base + e2,      i1 = base + 2 + e2;
          float w0 = (i0 < cnt) ? 1.f : 0.f, w1 = (i1 < cnt) ? 1.f : 0.f;
          int c0 = (i0 < cnt) ? i0 : 0,      c1 = (i1 < cnt) ? i1 : 0;
          const T* r0 = rbase + (size_t)c0 * REC;
          const T* r1 = rbase + (size_t)c1 * REC;
          int n0 = eb[c0].y, n1 = eb[c1].y;
          float s0_0 = ldv(r0,72), sA0 = ldv(r0,73), sA1 = ldv(r0,74), sA2 = ldv(r0,75);
          float s0_1 = ldv(r1,72), sB0 = ldv(r1,73), sB1 = ldv(r1,74), sB2 = ldv(r1,75);
          float a0v = ldv(r0, k32) * w0,            a1v = ldv(r1, k32) * w1;
          float b0v = ldv(r0, 32+k24) * (w0*m24),   b1v = ldv(r1, 32+k24) * (w1*m24);
          float e0v = ldv(emb, n0*32 + k32),        e1v = ldv(emb, n1*32 + k32);
          float g0v = ldv(f0,  n0*32 + k32),        g1v = ldv(f0,  n1*32 + k32);
          float h00 = ldv(f1, n0*72 + k24)*m24,     h10 = ldv(f1, n1*72 + k24)*m24;
          float h01 = ldv(f1, n0*72 + 24 + k24)*m24,h11 = ldv(f1, n1*72 + 24 + k24)*m24;
          float h02 = ldv(f1, n0*72 + 48 + k24)*m24,h12 = ldv(f1, n1*72 + 48 + k24)*m24;
          // edge 0
          float ve = a0v * s0_0;
          acc[0] = fmaf(ve, e0v, acc[0]);
          acc[4] = fmaf(ve, g0v, acc[4]);
          float rbek = b0v * e0v;
          acc[1] = fmaf(sA0, rbek, acc[1]);
          acc[2] = fmaf(sA1, rbek, acc[2]);
          acc[3] = fmaf(sA2, rbek, acc[3]);
          acc[5] = fmaf(ve, h00, acc[5]);
          acc[6] = fmaf(ve, h01, acc[6]);
          acc[7] = fmaf(ve, h02, acc[7]);
          float g3 = b0v * g0v;
          acc[8]  = fmaf(g3, sA0, acc[8]);
          acc[9]  = fmaf(g3, sA1, acc[9]);
          acc[10] = fmaf(g3, sA2, acc[10]);
          float sa;
          sa = b0v * sA0;
          acc[11] = fmaf(sa, h00, acc[11]); acc[12] = fmaf(sa, h01, acc[12]); acc[13] = fmaf(sa, h02, acc[13]);
          sa = b0v * sA1;
          acc[14] = fmaf(sa, h00, acc[14]); acc[15] = fmaf(sa, h01, acc[15]); acc[16] = fmaf(sa, h02, acc[16]);
          sa = b0v * sA2;
          acc[17] = fmaf(sa, h00, acc[17]); acc[18] = fmaf(sa, h01, acc[18]); acc[19] = fmaf(sa, h02, acc[19]);
          // edge 1
          ve = a1v * s0_1;
          acc[0] = fmaf(ve, e1v, acc[0]);
          acc[4] = fmaf(ve, g1v, acc[4]);
          rbek = b1v * e1v;
          acc[1] = fmaf(sB0, rbek, acc[1]);
          acc[2] = fmaf(sB1, rbek, acc[2]);
          acc[3] = fmaf(sB2, rbek, acc[3]);
          acc[5] = fmaf(ve, h10, acc[5]);
          acc[6] = fmaf(ve, h11, acc[6]);
          acc[7] = fmaf(ve, h12, acc[7]);
          g3 = b1v * g1v;
          acc[8]  = fmaf(g3, sB0, acc[8]);
          acc[9]  = fmaf(g3, sB1, acc[9]);
          acc[10] = fmaf(g3, sB2, acc[10]);
          sa = b1v * sB0;
          acc[11] = fmaf(sa, h10, acc[11]); acc[12] = fmaf(sa, h11, acc[12]); acc[13] = fmaf(sa, h12, acc[13]);
          sa = b1v * sB1;
          acc[14] = fmaf(sa, h10, acc[14]); acc[15] = fmaf(sa, h11, acc[15]); acc[16] = fmaf(sa, h12, acc[16]);
          sa = b1v * sB2;
          acc[17] = fmaf(sa, h10, acc[17]); acc[18] = fmaf(sa, h11, acc[18]); acc[19] = fmaf(sa, h12, acc[19]);
        }
      } else if (wv == 1) {
        // W1: d2 + (0,2,2),(1,2,1),(1,2,2); lanes (e4,k16), 8 edges/iter
        for (int base = 0; base < cnt; base += 8) {
          #pragma unroll
          for (int u = 0; u < 2; ++u) {
            int idx = base + 4*u + e4;
            float w = (idx < cnt) ? 1.f : 0.f;
            int ic  = (idx < cnt) ? idx : 0;
            const T* r = rbase + (size_t)ic * REC;
            int n = eb[ic].y;
            float rb0k = ldv(r, k16) * w;
            float rb1k = ldv(r, 32+k16) * w;
            float rb2k = ldv(r, 56+k16) * w;
            float s0 = ldv(r, 72);
            float s1a[3];
            #pragma unroll
            for (int m = 0; m < 3; ++m) s1a[m] = ldv(r, 73+m);
            float s2a[5];
            #pragma unroll
            for (int m = 0; m < 5; ++m) s2a[m] = ldv(r, 76+m);
            float ek = ldv(emb, n*32 + k16);
            float f2k[5];
            #pragma unroll
            for (int b = 0; b < 5; ++b) f2k[b] = ldv(f2, n*80 + b*16 + k16);
            float re = rb2k * ek;
            #pragma unroll
            for (int m = 0; m < 5; ++m) acc[m] = fmaf(s2a[m], re, acc[m]);
            float ve0 = s0 * rb0k;
            #pragma unroll
            for (int b = 0; b < 5; ++b) acc[5+b] = fmaf(ve0, f2k[b], acc[5+b]);
            #pragma unroll
            for (int aa = 0; aa < 3; ++aa) {
              float sa = rb1k * s1a[aa];
              #pragma unroll
              for (int b = 0; b < 5; ++b)
                acc[10+aa*5+b] = fmaf(sa, f2k[b], acc[10+aa*5+b]);
            }
          }
        }
      } else if (wv == 2) {
        // W2: (2,0,2),(2,1,1),(2,1,2)
        for (int base = 0; base < cnt; base += 8) {
          #pragma unroll
          for (int u = 0; u < 2; ++u) {
            int idx = base + 4*u + e4;
            float w = (idx < cnt) ? 1.f : 0.f;
            int ic  = (idx < cnt) ? idx : 0;
            const T* r = rbase + (size_t)ic * REC;
            int n = eb[ic].y;
            float rb2k = ldv(r, 56+k16) * w;
            float s2a[5];
            #pragma unroll
            for (int m = 0; m < 5; ++m) s2a[m] = ldv(r, 76+m);
            float f0k = ldv(f0, n*32 + k16);
            float f1k[3];
            #pragma unroll
            for (int b = 0; b < 3; ++b) f1k[b] = ldv(f1, n*72 + b*24 + k16);
            float g9 = rb2k * f0k;
            #pragma unroll
            for (int aa = 0; aa < 5; ++aa) acc[aa] = fmaf(g9, s2a[aa], acc[aa]);
            #pragma unroll
            for (int aa = 0; aa < 5; ++aa) {
              float sa = rb2k * s2a[aa];
              #pragma unroll
              for (int b = 0; b < 3; ++b)
                acc[5+aa*3+b] = fmaf(sa, f1k[b], acc[5+aa*3+b]);
            }
          }
        }
      } else {
        // W3: (2,2,0),(2,2,1),(2,2,2)
        for (int base = 0; base < cnt; base += 8) {
          #pragma unroll
          for (int u = 0; u < 2; ++u) {
            int idx = base + 4*u + e4;
            float w = (idx < cnt) ? 1.f : 0.f;
            int ic  = (idx < cnt) ? idx : 0;
            const T* r = rbase + (size_t)ic * REC;
            int n = eb[ic].y;
            float rb2k = ldv(r, 56+k16) * w;
            float s2a[5];
            #pragma unroll
            for (int m = 0; m < 5; ++m) s2a[m] = ldv(r, 76+m);
            float f2k[5];
            #pragma unroll
            for (int b = 0; b < 5; ++b) f2k[b] = ldv(f2, n*80 + b*16 + k16);
            #pragma unroll
            for (int aa = 0; aa < 5; ++aa) {
              float sa = rb2k * s2a[aa];
              #pragma unroll
              for (int b = 0; b < 5; ++b)
                acc[aa*5+b] = fmaf(sa, f2k[b], acc[aa*5+b]);
            }
          }
        }
      }
    } else {
      // -------- gathered fallback (chunked LDS staging, as before) --------
      for (int cbase = 0; cbase < cnt; cbase += 256) {
        int nch = cnt - cbase; if (nch > 256) nch = 256;
        __syncthreads();
        if (tix < nch) {
          int e = elist[beg + cbase + tix];
          sel[tix] = make_int2(e, neighbors[e]);
        }
        __syncthreads();
        if (wv == 0) {
          for (int base = 0; base < nch; base += 4) {
            #pragma unroll
            for (int u = 0; u < 2; ++u) {
              int idx = base + 2*u + e2;
              float w = (idx < nch) ? 1.f : 0.f;
              int ic  = (idx < nch) ? idx : 0;
              int2 en = sel[ic];
              int e = en.x, n = en.y;
              float s0 = ldv(sh0, e);
              float s1a0 = ldv(sh1, e*3+0), s1a1 = ldv(sh1, e*3+1), s1a2 = ldv(sh1, e*3+2);
              float rb0k = ldv(rb0, e*32 + k32) * w;
              float ek   = ldv(emb, n*32 + k32);
              float f0k  = ldv(f0,  n*32 + k32);
              float ve0 = s0 * rb0k;
              acc[0] = fmaf(ve0, ek, acc[0]);
              acc[4] = fmaf(ve0, f0k, acc[4]);
              if (k32 < 24) {
                float rb1k = ldv(rb1, e*24 + k32) * w;
                float f1k0 = ldv(f1, n*72 + k32);
                float f1k1 = ldv(f1, n*72 + 24 + k32);
                float f1k2 = ldv(f1, n*72 + 48 + k32);
                float rbek = rb1k * ek;
                acc[1] = fmaf(s1a0, rbek, acc[1]);
                acc[2] = fmaf(s1a1, rbek, acc[2]);
                acc[3] = fmaf(s1a2, rbek, acc[3]);
                acc[5] = fmaf(ve0, f1k0, acc[5]);
                acc[6] = fmaf(ve0, f1k1, acc[6]);
                acc[7] = fmaf(ve0, f1k2, acc[7]);
                float g3 = rb1k * f0k;
                acc[8]  = fmaf(g3, s1a0, acc[8]);
                acc[9]  = fmaf(g3, s1a1, acc[9]);
                acc[10] = fmaf(g3, s1a2, acc[10]);
                #pragma unroll
                for (int aa = 0; aa < 3; ++aa) {
                  float sa = rb1k * ((aa==0)?s1a0:(aa==1)?s1a1:s1a2);
                  acc[11+aa*3+0] = fmaf(sa, f1k0, acc[11+aa*3+0]);
                  acc[11+aa*3+1] = fmaf(sa, f1k1, acc[11+aa*3+1]);
                  acc[11+aa*3+2] = fmaf(sa, f1k2, acc[11+aa*3+2]);
                }
              }
            }
          }
        } else if (wv == 1) {
          for (int base = 0; base < nch; base += 8) {
            #pragma unroll
            for (int u = 0; u < 2; ++u) {
              int idx = base + 4*u + e4;
              float w = (idx < nch) ? 1.f : 0.f;
              int ic  = (idx < nch) ? idx : 0;
              int2 en = sel[ic];
              int e = en.x, n = en.y;
              float s0 = ldv(sh0, e);
              float s1a[3];
              #pragma unroll
              for (int m = 0; m < 3; ++m) s1a[m] = ldv(sh1, e*3+m);
              float s2a[5];
              #pragma unroll
              for (int m = 0; m < 5; ++m) s2a[m] = ldv(sh2, e*5+m);
              float rb0k = ldv(rb0, e*32 + k16) * w;
              float rb1k = ldv(rb1, e*24 + k16) * w;
              float rb2k = ldv(rb2, e*16 + k16) * w;
              float ek   = ldv(emb, n*32 + k16);
              float f2k[5];
              #pragma unroll
              for (int b = 0; b < 5; ++b) f2k[b] = ldv(f2, n*80 + b*16 + k16);
              float re = rb2k * ek;
              #pragma unroll
              for (int m = 0; m < 5; ++m) acc[m] = fmaf(s2a[m], re, acc[m]);
              float ve0 = s0 * rb0k;
              #pragma unroll
              for (int b = 0; b < 5; ++b) acc[5+b] = fmaf(ve0, f2k[b], acc[5+b]);
              #pragma unroll
              for (int aa = 0; aa < 3; ++aa) {
                float sa = rb1k * s1a[aa];
                #pragma unroll
                for (int b = 0; b < 5; ++b)
                  acc[10+aa*5+b] = fmaf(sa, f2k[b], acc[10+aa*5+b]);
              }
            }
          }
        } else if (wv == 2) {
          for (int base = 0; base < nch; base += 8) {
            #pragma unroll
            for (int u = 0; u < 2; ++u) {
              int idx = base + 4*u + e4;
              float w = (idx < nch) ? 1.f : 0.f;
              int ic  = (idx < nch) ? idx : 0;
              int2 en = sel[ic];
              int e = en.x, n = en.y;
              float s2a[5];
              #pragma unroll
              for (int m = 0; m < 5; ++m) s2a[m] = ldv(sh2, e*5+m);
              float rb2k = ldv(rb2, e*16 + k16) * w;
              float f0k  = ldv(f0,  n*32 + k16);
              float f1k[3];
              #pragma unroll
              for (int b = 0; b < 3; ++b) f1k[b] = ldv(f1, n*72 + b*24 + k16);
              float g9 = rb2k * f0k;
              #pragma unroll
              for (int aa = 0; aa < 5; ++aa) acc[aa] = fmaf(g9, s2a[aa], acc[aa]);
              #pragma unroll
              for (int aa = 0; aa < 5; ++aa) {
                float sa = rb2k * s2a[aa];
                #pragma unroll
                for (int b = 0; b < 3; ++b)
                  acc[5+aa*3+b] = fmaf(sa, f1k[b], acc[5+aa*3+b]);
              }
            }
          }
        } else {
          for (int base = 0; base < nch; base += 8) {
            #pragma unroll
            for (int u = 0; u < 2; ++u) {
              int idx = base + 4*u + e4;
              float w = (idx < nch) ? 1.f : 0.f;
              int ic  = (idx < nch) ? idx : 0;
              int2 en = sel[ic];
              int e = en.x, n = en.y;
              float s2a[5];
              #pragma unroll
              for (int m = 0; m < 5; ++m) s2a[m] = ldv(sh2, e*5+m);
              float rb2k = ldv(rb2, e*16 + k16) * w;
              float f2k[5];
              #pragma unroll
              for (int b = 0; b < 5; ++b) f2k[b] = ldv(f2, n*80 + b*16 + k16);
              #pragma unroll
              for (int aa = 0; aa < 5; ++aa) {
                float sa = rb2k * s2a[aa];
                #pragma unroll
                for (int b = 0; b < 5; ++b)
                  acc[aa*5+b] = fmaf(sa, f2k[b], acc[aa*5+b]);
              }
            }
          }
        }
      }
    }

    // ---- cross-lane reductions + per-atom cg contraction ----
    if (wv == 0) {
      #pragma unroll
      for (int i = 0; i < 20; ++i) acc[i] += __shfl_xor(acc[i], 32);
      const float* C000 = cgf + 0;
      const float* C011 = cgf + 1;
      const float* C101 = cgf + 35;
      const float* C110 = cgf + 44;
      const float* C111 = cgf + 53;
      const float* C112 = cgf + 80;
      float r[16];
      r[0] = C000[0] * acc[4];
      #pragma unroll
      for (int M = 0; M < 3; ++M) {
        float t = 0.f;
        #pragma unroll
        for (int b = 0; b < 3; ++b) t = fmaf(acc[5+b], C011[b*3+M], t);
        r[1+M] = t;
      }
      #pragma unroll
      for (int M = 0; M < 3; ++M) {
        float t = 0.f;
        #pragma unroll
        for (int aa = 0; aa < 3; ++aa) t = fmaf(acc[8+aa], C101[aa*3+M], t);
        r[4+M] = t;
      }
      {
        float t = 0.f;
        #pragma unroll
        for (int q = 0; q < 9; ++q) t = fmaf(acc[11+q], C110[q], t);
        r[7] = t;
      }
      #pragma unroll
      for (int M = 0; M < 3; ++M) {
        float t = 0.f;
        #pragma unroll
        for (int q = 0; q < 9; ++q) t = fmaf(acc[11+q], C111[q*3+M], t);
        r[8+M] = t;
      }
      #pragma unroll
      for (int M = 0; M < 5; ++M) {
        float t = 0.f;
        #pragma unroll
        for (int q = 0; q < 9; ++q) t = fmaf(acc[11+q], C112[q*5+M], t);
        r[11+M] = t;
      }
      acc[4] = r[0];
      #pragma unroll
      for (int M = 0; M < 3; ++M) acc[5+M]  = r[1+M];
      #pragma unroll
      for (int M = 0; M < 3; ++M) acc[8+M]  = r[4+M];
      acc[11] = r[7];
      #pragma unroll
      for (int M = 0; M < 3; ++M) acc[12+M] = r[8+M];
      #pragma unroll
      for (int M = 0; M < 5; ++M) acc[15+M] = r[11+M];
    } else if (wv == 1) {
      #pragma unroll
      for (int i = 0; i < 25; ++i) {
        acc[i] += __shfl_xor(acc[i], 16);
        acc[i] += __shfl_xor(acc[i], 32);
      }
      const float* C022 = cgf + 10;
      const float* C121 = cgf + 125;
      const float* C122 = cgf + 170;
      float r[13];
      #pragma unroll
      for (int M = 0; M < 5; ++M) {
        float t = 0.f;
        #pragma unroll
        for (int b = 0; b < 5; ++b) t = fmaf(acc[5+b], C022[b*5+M], t);
        r[M] = t;
      }
      #pragma unroll
      for (int M = 0; M < 3; ++M) {
        float t = 0.f;
        #pragma unroll
        for (int q = 0; q < 15; ++q) t = fmaf(acc[10+q], C121[q*3+M], t);
        r[5+M] = t;
      }
      #pragma unroll
      for (int M = 0; M < 5; ++M) {
        float t = 0.f;
        #pragma unroll
        for (int q = 0; q < 15; ++q) t = fmaf(acc[10+q], C122[q*5+M], t);
        r[8+M] = t;
      }
      #pragma unroll
      for (int M = 0; M < 5; ++M) acc[5+M]  = r[M];
      #pragma unroll
      for (int M = 0; M < 3; ++M) acc[10+M] = r[5+M];
      #pragma unroll
      for (int M = 0; M < 5; ++M) acc[13+M] = r[8+M];
    } else if (wv == 2) {
      #pragma unroll
      for (int i = 0; i < 20; ++i) {
        acc[i] += __shfl_xor(acc[i], 16);
        acc[i] += __shfl_xor(acc[i], 32);
      }
      const float* C202 = cgf + 245;
      const float* C211 = cgf + 270;
      const float* C212 = cgf + 315;
      float r[13];
      #pragma unroll
      for (int M = 0; M < 5; ++M) {
        float t = 0.f;
        #pragma unroll
        for (int aa = 0; aa < 5; ++aa) t = fmaf(acc[aa], C202[aa*5+M], t);
        r[M] = t;
      }
      #pragma unroll
      for (int M = 0; M < 3; ++M) {
        float t = 0.f;
        #pragma unroll
        for (int q = 0; q < 15; ++q) t = fmaf(acc[5+q], C211[q*3+M], t);
        r[5+M] = t;
      }
      #pragma unroll
      for (int M = 0; M < 5; ++M) {
        float t = 0.f;
        #pragma unroll
        for (int q = 0; q < 15; ++q) t = fmaf(acc[5+q], C212[q*5+M], t);
        r[8+M] = t;
      }
      #pragma unroll
      for (int M = 0; M < 5; ++M) acc[M]   = r[M];
      #pragma unroll
      for (int M = 0; M < 3; ++M) acc[5+M] = r[5+M];
      #pragma unroll
      for (int M = 0; M < 5; ++M) acc[8+M] = r[8+M];
    } else {
      #pragma unroll
      for (int i = 0; i < 25; ++i) {
        acc[i] += __shfl_xor(acc[i], 16);
        acc[i] += __shfl_xor(acc[i], 32);
      }
      const float* C220 = cgf + 390;
      const float* C221 = cgf + 415;
      const float* C222 = cgf + 490;
      float r[9];
      {
        float t = 0.f;
        #pragma unroll
        for (int q = 0; q < 25; ++q) t = fmaf(acc[q], C220[q], t);
        r[0] = t;
      }
      #pragma unroll
      for (int M = 0; M < 3; ++M) {
        float t = 0.f;
        #pragma unroll
        for (int q = 0; q < 25; ++q) t = fmaf(acc[q], C221[q*3+M], t);
        r[1+M] = t;
      }
      #pragma unroll
      for (int M = 0; M < 5; ++M) {
        float t = 0.f;
        #pragma unroll
        for (int q = 0; q < 25; ++q) t = fmaf(acc[q], C222[q*5+M], t);
        r[4+M] = t;
      }
      #pragma unroll
      for (int i = 0; i < 9; ++i) acc[i] = r[i];
    }

    // ---------------- epilogues ----------------
    if constexpr (EPI == 1) {
      if (wv == 0) {
        if (lane < 32) {
          stv(out, O0 + a*32 + k32, acc[0]);
          atomicAdd(&s1p[(0+k32)*64+ab], acc[4]*acc[4]);
          if (k32 < 24) {
            #pragma unroll
            for (int m = 0; m < 3; ++m) stv(out, O1 + a*72 + m*24 + k32, acc[1+m]);
            atomicAdd(&s1p[(32+k32)*64+ab], acc[11]*acc[11]);
            float q;
            q = acc[5]*acc[5]+acc[6]*acc[6]+acc[7]*acc[7];
            atomicAdd(&s1p[(72+k32)*64+ab], q);
            q = acc[8]*acc[8]+acc[9]*acc[9]+acc[10]*acc[10];
            atomicAdd(&s1p[(96+k32)*64+ab], q);
            q = acc[12]*acc[12]+acc[13]*acc[13]+acc[14]*acc[14];
            atomicAdd(&s1p[(152+k32)*64+ab], q);
            q = acc[15]*acc[15]+acc[16]*acc[16]+acc[17]*acc[17]
              + acc[18]*acc[18]+acc[19]*acc[19];
            atomicAdd(&s1p[(208+k32)*64+ab], q);
          }
        }
      } else if (wv == 1) {
        if (lane < 16) {
          #pragma unroll
          for (int m = 0; m < 5; ++m) stv(out, O2 + a*80 + m*16 + k16, acc[m]);
          float q;
          q = acc[5]*acc[5]+acc[6]*acc[6]+acc[7]*acc[7]+acc[8]*acc[8]+acc[9]*acc[9];
          atomicAdd(&s1p[(192+k16)*64+ab], q);
          q = acc[10]*acc[10]+acc[11]*acc[11]+acc[12]*acc[12];
          atomicAdd(&s1p[(120+k16)*64+ab], q);
          q = acc[13]*acc[13]+acc[14]*acc[14]+acc[15]*acc[15]
            + acc[16]*acc[16]+acc[17]*acc[17];
          atomicAdd(&s1p[(264+k16)*64+ab], q);
        }
      } else if (wv == 2) {
        if (lane < 16) {
          float q;
          q = acc[0]*acc[0]+acc[1]*acc[1]+acc[2]*acc[2]+acc[3]*acc[3]+acc[4]*acc[4];
          atomicAdd(&s1p[(232+k16)*64+ab], q);
          q = acc[5]*acc[5]+acc[6]*acc[6]+acc[7]*acc[7];
          atomicAdd(&s1p[(136+k16)*64+ab], q);
          q = acc[8]*acc[8]+acc[9]*acc[9]+acc[10]*acc[10]
            + acc[11]*acc[11]+acc[12]*acc[12];
          atomicAdd(&s1p[(280+k16)*64+ab], q);
        }
      } else {
        if (lane < 16) {
          atomicAdd(&s1p[(56+k16)*64+ab], acc[0]*acc[0]);
          float q;
          q = acc[1]*acc[1]+acc[2]*acc[2]+acc[3]*acc[3];
          atomicAdd(&s1p[(176+k16)*64+ab], q);
          q = acc[4]*acc[4]+acc[5]*acc[5]+acc[6]*acc[6]
            + acc[7]*acc[7]+acc[8]*acc[8];
          atomicAdd(&s1p[(248+k16)*64+ab], q);
        }
      }
    }

    if constexpr (EPI == 2) {
      if (wv == 0) {
        if (lane < 32) {
          L[k32] = acc[4]*inv[k32];
          if (k32 < 24) {
            L[32+k32] = acc[11]*inv[32+k32];
            #pragma unroll
            for (int M = 0; M < 3; ++M) L[72+M*80+k32]     = acc[5+M]*inv[72+k32];
            #pragma unroll
            for (int M = 0; M < 3; ++M) L[72+M*80+24+k32]  = acc[8+M]*inv[96+k32];
            #pragma unroll
            for (int M = 0; M < 3; ++M) L[312+M*40+k32]    = acc[12+M]*inv[152+k32];
            #pragma unroll
            for (int M = 0; M < 5; ++M) L[432+M*72+16+k32] = acc[15+M]*inv[208+k32];
          }
        }
      } else if (wv == 1) {
        if (lane < 16) {
          #pragma unroll
          for (int M = 0; M < 5; ++M) L[432+M*72+k16]    = acc[5+M]*inv[192+k16];
          #pragma unroll
          for (int M = 0; M < 3; ++M) L[72+M*80+48+k16]  = acc[10+M]*inv[120+k16];
          #pragma unroll
          for (int M = 0; M < 5; ++M) L[792+M*32+k16]    = acc[13+M]*inv[264+k16];
        }
      } else if (wv == 2) {
        if (lane < 16) {
          #pragma unroll
          for (int M = 0; M < 5; ++M) L[432+M*72+40+k16] = acc[0+M]*inv[232+k16];
          #pragma unroll
          for (int M = 0; M < 3; ++M) L[72+M*80+64+k16]  = acc[5+M]*inv[136+k16];
          #pragma unroll
          for (int M = 0; M < 5; ++M) L[792+M*32+16+k16] = acc[8+M]*inv[280+k16];
        }
      } else {
        if (lane < 16) {
          L[56+k16] = acc[0]*inv[56+k16];
          #pragma unroll
          for (int M = 0; M < 3; ++M) L[312+M*40+24+k16] = acc[1+M]*inv[176+k16];
          #pragma unroll
          for (int M = 0; M < 5; ++M) L[432+M*72+56+k16] = acc[4+M]*inv[248+k16];
        }
      }
      __syncthreads();
      int t = threadIdx.x;
      float y2[5] = {0.f,0.f,0.f,0.f,0.f};
      for (int tau = t; tau < 336; tau += 256) {
        int ls = 0;
        while (tau >= c_cum[ls+1]) ++ls;
        int rem = tau - c_cum[ls];
        int kn = c_kout[ls], fin = c_fin[ls];
        int M = rem / kn, ko = rem - M*kn;
        const T* W = (const T*)lp.W[ls];
        float y = ldv((const T*)lp.B[ls], ko);
        const float* xv = &L[c_xb[ls] + M*fin];
        for (int f = 0; f < fin; ++f) y = fmaf(xv[f], ldv(W, f*kn+ko), y);
        stv(out, c_yoff[ls] + (a*c_Ms[ls] + M)*kn + ko, y);
        y2[ls] += y*y;
      }
      #pragma unroll
      for (int i = 0; i < 5; ++i) {
        y2[i] += __shfl_xor(y2[i], 1);  y2[i] += __shfl_xor(y2[i], 2);
        y2[i] += __shfl_xor(y2[i], 4);  y2[i] += __shfl_xor(y2[i], 8);
        y2[i] += __shfl_xor(y2[i], 16); y2[i] += __shfl_xor(y2[i], 32);
      }
      if (lane == 0) {
        #pragma unroll
        for (int i = 0; i < 5; ++i) red[wv][i] = y2[i];
      }
      __syncthreads();
      if (t == 0) {
        #pragma unroll
        for (int i = 0; i < 5; ++i)
          atomicAdd(&s2p[i*64 + ab], red[0][i]+red[1][i]+red[2][i]+red[3][i]);
      }
    }
  }
}

// ---------------- reducers ----------------
__global__ void k_red1(const float* __restrict__ s1p, float* __restrict__ inv) {
  int ch = blockIdx.x, lane = threadIdx.x;
  float v = s1p[ch*64 + lane];
  v += __shfl_xor(v, 1);  v += __shfl_xor(v, 2);  v += __shfl_xor(v, 4);
  v += __shfl_xor(v, 8);  v += __shfl_xor(v, 16); v += __shfl_xor(v, 32);
  if (lane == 0) {
    float rows = (ch < 72) ? 10000.f : (ch < 192) ? 30000.f : 50000.f;
    inv[ch] = rsqrtf(v/rows + 1e-12f);
  }
}

__global__ void k_red2(const float* __restrict__ s2p, float* __restrict__ ws2) {
  int ls = blockIdx.x, lane = threadIdx.x;
  float v = s2p[ls*64 + lane];
  v += __shfl_xor(v, 1);  v += __shfl_xor(v, 2);  v += __shfl_xor(v, 4);
  v += __shfl_xor(v, 8);  v += __shfl_xor(v, 16); v += __shfl_xor(v, 32);
  if (lane == 0) ws2[ls] = v;
}

// ---------------- final global RMS scale, in place ----------------
template<typename T>
__global__ void k_scale(const float* __restrict__ ws2, T* __restrict__ out,
                        const int* __restrict__ flag) {
  if (flag[0] != dtid<T>()) return;
  int i = blockIdx.x*blockDim.x + threadIdx.x;
  if (i >= 3360000) return;
  int ls = (i < 320000) ? 0 : (i < 1040000) ? 1 : (i < 1760000) ? 2 : (i < 2560000) ? 3 : 4;
  float scale = rsqrtf(ws2[ls] / (float)c_numel[ls] + 1e-12f);
  stv(out, OY + i, ldv((const T*)out, OY + i) * scale);
}

template<typename T>
static void launch_chain(void* const* d_in, T* out, float* wsf, int* wsi,
                         Ptrs15 cg, LinP lp, bool strm, hipStream_t stream) {
  const T* rb0 = (const T*)d_in[0];
  const T* rb1 = (const T*)d_in[1];
  const T* rb2 = (const T*)d_in[2];
  const T* sh0 = (const T*)d_in[3];
  const T* sh1 = (const T*)d_in[4];
  const T* sh2 = (const T*)d_in[5];
  const T* emb = (const T*)d_in[6];
  const T* f0  = (const T*)d_in[7];
  const T* f1  = (const T*)d_in[8];
  const T* f2  = (const T*)d_in[9];
  const int* centers   = (const int*)d_in[35];
  const int* neighbors = (const int*)d_in[36];
  const int* flag = wsi + IFLAG;
  T* erec = (T*)(wsf + SEREC);

  k_cg<T><<<3, 256, 0, stream>>>(cg, wsf, flag);
  if (strm) {
    k_pack<T><<<2048, 256, 0, stream>>>(rb0, rb1, rb2, sh0, sh1, sh2,
        centers, neighbors, wsi+IOFFS, wsi+ICURS, (int2*)(wsi+IELIST), erec, flag);
    k_main<T,3><<<2500, 256, 0, stream>>>(rb0, rb1, rb2, sh0, sh1, sh2, emb, f0, f1, f2,
        neighbors, wsi+IOFFS, wsi+IELIST, erec, wsf+SCG, wsf+SS1P, nullptr, nullptr,
        lp, out, flag);
    k_red1<<<296, 64, 0, stream>>>(wsf+SS1P, wsf+SINV);
    k_main<T,4><<<2500, 256, 0, stream>>>(rb0, rb1, rb2, sh0, sh1, sh2, emb, f0, f1, f2,
        neighbors, wsi+IOFFS, wsi+IELIST, erec, wsf+SCG, nullptr, wsf+SINV, wsf+SS2P,
        lp, out, flag);
  } else {
    k_scatterT<T><<<(N_EDGES+255)/256, 256, 0, stream>>>(centers, wsi+IOFFS,
        wsi+ICURS, wsi+IELIST, flag);
    k_main<T,1><<<2500, 256, 0, stream>>>(rb0, rb1, rb2, sh0, sh1, sh2, emb, f0, f1, f2,
        neighbors, wsi+IOFFS, wsi+IELIST, nullptr, wsf+SCG, wsf+SS1P, nullptr, nullptr,
        lp, out, flag);
    k_red1<<<296, 64, 0, stream>>>(wsf+SS1P, wsf+SINV);
    k_main<T,2><<<2500, 256, 0, stream>>>(rb0, rb1, rb2, sh0, sh1, sh2, emb, f0, f1, f2,
        neighbors, wsi+IOFFS, wsi+IELIST, nullptr, wsf+SCG, nullptr, wsf+SINV, wsf+SS2P,
        lp, out, flag);
  }
  k_red2<<<5, 64, 0, stream>>>(wsf+SS2P, wsf+SWS2);
  k_scale<T><<<(3360000+255)/256, 256, 0, stream>>>(wsf+SWS2, out, flag);
}

extern "C" void kernel_launch(void* const* d_in, const int* in_sizes, int n_in,
                              void* d_out, int out_size, void* d_ws, size_t ws_size,
                              hipStream_t stream) {
  float* wsf = (float*)d_ws;
  int*   wsi = (int*)(wsf + SINTS);
  const int* centers   = (const int*)d_in[35];

  // stream-mode workspace requirement per dtype: ints region + packed records
  size_t need_bf16 = (size_t)SEREC*4 + (size_t)N_EDGES*REC*2 + 256;
  size_t need_f32  = (size_t)SEREC*4 + (size_t)N_EDGES*REC*4 + 256;
  bool strm_bf16 = ws_size >= need_bf16;
  bool strm_f32  = ws_size >= need_f32;

  // Host-side dtype detection.
  // know: 0 = bf16 only, 1 = fp32 only, -1 = ambiguous -> dual chain + probe.
  int know = -1;
  if (in_sizes) {
    long long nb = (long long)in_sizes[0];         // rb0: 200000*32 elems
    if (nb == (long long)N_EDGES*32*2) know = 0;
    else if (nb == (long long)N_EDGES*32*4) know = 1;
  }
  if (know < 0) {
    long long ob = (long long)out_size;            // 5.2M output elems
    if (ob == (long long)OUT_ELEMS*2) know = 0;
    else if (ob == (long long)OUT_ELEMS*4) know = 1;
  }

  Ptrs15 cg;
  for (int i = 0; i < 15; ++i) cg.p[i] = d_in[10+i];
  LinP lp;
  lp.W[0] = d_in[25]; lp.B[0] = d_in[26];
  lp.W[1] = d_in[27]; lp.B[1] = d_in[28];
  lp.W[2] = d_in[29]; lp.B[2] = d_in[30];
  lp.W[3] = d_in[31]; lp.B[3] = d_in[32];
  lp.W[4] = d_in[33]; lp.B[4] = d_in[34];

  k_zero<<<154, 256, 0, stream>>>(wsf, wsi,
                                  (const unsigned short*)d_in[0],
                                  (const unsigned short*)d_in[6]);
  k_hist<<<(N_EDGES+255)/256, 256, 0, stream>>>(centers, wsi+ICOUNT);
  k_scan<<<1, 1024, 0, stream>>>(wsi+ICOUNT, wsi+IOFFS);

  if (know != 1) launch_chain<bf16 >(d_in, (bf16*)d_out,  wsf, wsi, cg, lp, strm_bf16, stream);
  if (know != 0) launch_chain<float>(d_in, (float*)d_out, wsf, wsi, cg, lp, strm_f32, stream);
}

// Round 4
// 516.826 us; speedup vs baseline: 1.4623x; 1.4623x over previous
//
#include <hip/hip_runtime.h>
#include <hip/hip_bf16.h>

typedef __hip_bfloat16 bf16;

#define N_ATOMS 10000
#define N_EDGES 200000

// ======== float region of ws (float offsets) ========
#define SCG   0        // 615 cg coeffs f32
#define SINV  616      // 296 inv per channel (+pad)
#define SS1P  1024     // 296*64 partials
#define SS2P  19968    // 5*64 partials
#define SWS2  20288    // 5 (+pad)
#define SINTS 20352    // int region starts here (float idx)
// ======== int region (offsets in ints, relative to SINTS) ========
#define IFLAG  0
#define ICOUNT 16      // 10000
#define IOFFS  10016   // 10001 (+pad)
#define ICURS  20032   // 10000
#define IELIST 30032   // 200000 ints
#define INTS_END 230032
#define SXACC (SINTS + INTS_END)
#define BIG_FLOATS (SXACC + 952*N_ATOMS)      // ~39.1 MB

// ---- d_out element offsets ----
#define O0 0
#define O1 320000
#define O2 1040000
#define OY 1840000
#define OUT_ELEMS 5200000

__device__ __forceinline__ float b2f(bf16 x){ return __bfloat162float(x); }
__device__ __forceinline__ bf16  f2b(float x){ return __float2bfloat16(x); }

__device__ __forceinline__ float ldv(const float* p, int i){ return p[i]; }
__device__ __forceinline__ float ldv(const bf16*  p, int i){ return b2f(p[i]); }
__device__ __forceinline__ void  stv(float* p, int i, float v){ p[i] = v; }
__device__ __forceinline__ void  stv(bf16*  p, int i, float v){ p[i] = f2b(v); }

// 4-element vector copy (global->LDS staging)
__device__ __forceinline__ void v4cp(bf16* d, const bf16* s){
  *reinterpret_cast<ushort4*>(d) = *reinterpret_cast<const ushort4*>(s);
}
__device__ __forceinline__ void v4cp(float* d, const float* s){
  *reinterpret_cast<float4*>(d) = *reinterpret_cast<const float4*>(s);
}

template<typename T> __device__ __forceinline__ int dtid();
template<> __device__ __forceinline__ int dtid<bf16>(){ return 0; }
template<> __device__ __forceinline__ int dtid<float>(){ return 1; }

struct Ptrs15 { const void* p[15]; };
struct LinP   { const void* W[5]; const void* B[5]; };

__constant__ int c_cg_sizes[15] = {1,9,25,9,9,27,45,45,75,25,45,75,25,75,125};
__constant__ int c_fin[5]   = {72,80,40,72,32};
__constant__ int c_kout[5]  = {32,24,24,16,16};
__constant__ int c_yoff[5]  = {OY+0, OY+320000, OY+1040000, OY+1760000, OY+2560000};
__constant__ int c_numel[5] = {320000,720000,720000,800000,800000};
__constant__ int c_cum[6]   = {0,32,104,176,256,336};
__constant__ int c_xb[5]    = {0,72,312,432,792};
__constant__ int c_Ms[5]    = {1,3,3,5,5};

// ---------------- zero + dtype probe (fallback path) ----------------
__global__ void k_zero(float* wsf, int* wsi,
                       const unsigned short* rb0u, const unsigned short* embu) {
  if (blockIdx.x == 0 && threadIdx.x < 64) {
    int lane = threadIdx.x;
    int bad = 0;
    for (int i = lane; i < 256; i += 64) {
      unsigned u1 = ((unsigned)rb0u[2*i]) << 16;
      unsigned u2 = ((unsigned)embu[2*i]) << 16;
      float v1 = __uint_as_float(u1);
      float v2 = __uint_as_float(u2);
      if (!(fabsf(v1) < 1e9f) || !(fabsf(v2) < 1e9f)) bad = 1;
    }
    unsigned long long any = __ballot(bad);
    if (lane == 0) wsi[IFLAG] = (any != 0ULL) ? 1 : 0;   // 1 = fp32, 0 = bf16
  }
  int i = blockIdx.x*blockDim.x + threadIdx.x;
  if (i < N_ATOMS) wsi[ICOUNT + i] = 0;
  int j = i - N_ATOMS;
  if (j >= 0 && j < N_ATOMS) wsi[ICURS + j] = 0;
  j -= N_ATOMS;
  if (j >= 0 && j < 18944) wsf[SS1P + j] = 0.f;
  j -= 18944;
  if (j >= 0 && j < 325) wsf[SS2P + j] = 0.f;
}

template<typename T>
__global__ void k_cg(Ptrs15 cg, float* wsf, const int* flag) {
  if (flag[0] != dtid<T>()) return;
  int i = blockIdx.x*blockDim.x + threadIdx.x;
  if (i >= 615) return;
  int s = 0, off = i;
  while (off >= c_cg_sizes[s]) { off -= c_cg_sizes[s]; ++s; }
  wsf[SCG + i] = ldv((const T*)cg.p[s], off);
}

__global__ void k_hist(const int* __restrict__ centers, int* __restrict__ counts) {
  int e = blockIdx.x*blockDim.x + threadIdx.x;
  if (e < N_EDGES) atomicAdd(&counts[centers[e]], 1);
}

__global__ void k_scan(const int* __restrict__ counts, int* __restrict__ offs) {
  __shared__ int part[1024];
  int t = threadIdx.x;
  int base = t*10;
  int s = 0;
  for (int i = 0; i < 10; ++i) { int idx = base+i; if (idx < N_ATOMS) s += counts[idx]; }
  part[t] = s;
  __syncthreads();
  for (int d = 1; d < 1024; d <<= 1) {
    int v = part[t];
    int add = (t >= d) ? part[t-d] : 0;
    __syncthreads();
    part[t] = v + add;
    __syncthreads();
  }
  int run = (t == 0) ? 0 : part[t-1];
  for (int i = 0; i < 10; ++i) {
    int idx = base+i;
    if (idx < N_ATOMS) { offs[idx] = run; run += counts[idx]; }
  }
  if (t == 1023) offs[N_ATOMS] = part[1023];
}

__global__ void k_scatter(const int* __restrict__ centers, const int* __restrict__ offs,
                          int* __restrict__ cursors, int* __restrict__ elist) {
  int e = blockIdx.x*blockDim.x + threadIdx.x;
  if (e < N_EDGES) {
    int c = centers[e];
    int p = atomicAdd(&cursors[c], 1);
    elist[offs[c] + p] = e;
  }
}

// ---------------- main K-loop: 1 atom/block, 4 wave-specialized waves ----------
// Round-4: cooperative LDS staging. Per 32-edge chunk all 256 threads stage
// edge data (SE) AND gathered neighbor rows (SN) with wide v4 loads -> the
// block's ~300 line requests issue in one deep burst (high MLP), each line
// fetched once (dedupes the 4-wave re-reads). Compute waves read LDS only.
// MODE 0: EPI1 + x->xout (big).  MODE 1: EPI1.  MODE 2: EPI2 (norm+linear).
template<typename T, int MODE>
__global__ __launch_bounds__(256) void k_main(
    const T* __restrict__ rb0, const T* __restrict__ rb1, const T* __restrict__ rb2,
    const T* __restrict__ sh0, const T* __restrict__ sh1, const T* __restrict__ sh2,
    const T* __restrict__ emb, const T* __restrict__ f0, const T* __restrict__ f1,
    const T* __restrict__ f2, const int* __restrict__ neighbors,
    const int* __restrict__ offs, const int* __restrict__ elist,
    const float* __restrict__ cgf, float* __restrict__ s1p,
    const float* __restrict__ inv, float* __restrict__ s2p,
    float* __restrict__ xout, LinP lp, T* __restrict__ out,
    const int* __restrict__ flag)
{
  if (flag[0] != dtid<T>()) return;
  int lane = threadIdx.x & 63;
  int wv   = threadIdx.x >> 6;
  int tix  = threadIdx.x;
  int a = blockIdx.x;
  int beg = offs[a];
  int cnt = offs[a+1] - beg;
  int k32 = lane & 31, e2 = lane >> 5;
  int k16 = lane & 15, e4 = lane >> 4;
  int ab = a & 63;

  __shared__ int2 sel[32];
  __shared__ T SE[32][84];   // [0:32) rb0 [32:56) rb1 [56:72) rb2 [72] sh0 [73:76) sh1 [76:81) sh2
  __shared__ T SN[32][216];  // [0:32) emb [32:64) f0 [64:136) f1 [136:216) f2
  __shared__ __align__(16) float L[952];
  __shared__ float red[4][5];

  float acc[25];
  #pragma unroll
  for (int i = 0; i < 25; ++i) acc[i] = 0.f;

  for (int cbase = 0; cbase < cnt; cbase += 32) {
    int nch = cnt - cbase; if (nch > 32) nch = 32;
    __syncthreads();   // protect SE/SN/sel overwrite across chunks
    if (tix < nch) {
      int e = elist[beg + cbase + tix];
      sel[tix] = make_int2(e, neighbors[e]);
    }
    __syncthreads();
    {
      int i = tix >> 3, p = tix & 7;
      if (i < nch) {
        int e = sel[i].x, n = sel[i].y;
        v4cp(&SE[i][p*4], rb0 + e*32 + p*4);
        if (p < 6) v4cp(&SE[i][32 + p*4], rb1 + e*24 + p*4);
        if (p < 4) v4cp(&SE[i][56 + p*4], rb2 + e*16 + p*4);
        if (p == 0) { SE[i][72] = sh0[e]; SE[i][80] = sh2[e*5+4]; }
        else if (p < 4) SE[i][72+p] = sh1[e*3 + p-1];
        else            SE[i][72+p] = sh2[e*5 + p-4];
        #pragma unroll
        for (int uu = 0; uu < 7; ++uu) {
          int g = p + uu*8;
          if (g < 54) {
            int ch = g*4;
            const T* src; int off;
            if (ch < 32)       { src = emb; off = n*32 + ch; }
            else if (ch < 64)  { src = f0;  off = n*32 + ch - 32; }
            else if (ch < 136) { src = f1;  off = n*72 + ch - 64; }
            else               { src = f2;  off = n*80 + ch - 136; }
            v4cp(&SN[i][ch], src + off);
          }
        }
      }
    }
    __syncthreads();

    if (wv == 0) {
      // ---- W0: l1-sector pairs, lanes (e2,k32), 4 edges/iter ----
      // acc: 0=d0, 1..3=d1, 4=S000, 5..7=S011[b], 8..10=S101[a], 11..19=S11[a*3+b]
      for (int base = 0; base < nch; base += 4) {
        #pragma unroll
        for (int u = 0; u < 2; ++u) {
          int idx = base + 2*u + e2;
          float w = (idx < nch) ? 1.f : 0.f;
          int ic  = (idx < nch) ? idx : 0;
          const T* rE = SE[ic];
          const T* rN = SN[ic];
          float s0 = ldv(rE,72);
          float s1a0 = ldv(rE,73), s1a1 = ldv(rE,74), s1a2 = ldv(rE,75);
          float rb0k = ldv(rE, k32) * w;
          float ek   = ldv(rN, k32);
          float f0k  = ldv(rN, 32+k32);
          float ve0 = s0 * rb0k;
          acc[0] = fmaf(ve0, ek, acc[0]);
          acc[4] = fmaf(ve0, f0k, acc[4]);
          if (k32 < 24) {
            float rb1k = ldv(rE, 32+k32) * w;
            float f1k0 = ldv(rN, 64+k32);
            float f1k1 = ldv(rN, 64+24+k32);
            float f1k2 = ldv(rN, 64+48+k32);
            float rbek = rb1k * ek;
            acc[1] = fmaf(s1a0, rbek, acc[1]);
            acc[2] = fmaf(s1a1, rbek, acc[2]);
            acc[3] = fmaf(s1a2, rbek, acc[3]);
            acc[5] = fmaf(ve0, f1k0, acc[5]);
            acc[6] = fmaf(ve0, f1k1, acc[6]);
            acc[7] = fmaf(ve0, f1k2, acc[7]);
            float g3 = rb1k * f0k;
            acc[8]  = fmaf(g3, s1a0, acc[8]);
            acc[9]  = fmaf(g3, s1a1, acc[9]);
            acc[10] = fmaf(g3, s1a2, acc[10]);
            #pragma unroll
            for (int aa = 0; aa < 3; ++aa) {
              float sa = rb1k * ((aa==0)?s1a0:(aa==1)?s1a1:s1a2);
              acc[11+aa*3+0] = fmaf(sa, f1k0, acc[11+aa*3+0]);
              acc[11+aa*3+1] = fmaf(sa, f1k1, acc[11+aa*3+1]);
              acc[11+aa*3+2] = fmaf(sa, f1k2, acc[11+aa*3+2]);
            }
          }
        }
      }
    } else if (wv == 1) {
      // ---- W1: d2 + (0,2,2),(1,2,1),(1,2,2); lanes (e4,k16), 8 edges/iter ----
      // acc: 0..4=d2, 5..9=S022[b], 10..24=S12[a*5+b]
      for (int base = 0; base < nch; base += 8) {
        #pragma unroll
        for (int u = 0; u < 2; ++u) {
          int idx = base + 4*u + e4;
          float w = (idx < nch) ? 1.f : 0.f;
          int ic  = (idx < nch) ? idx : 0;
          const T* rE = SE[ic];
          const T* rN = SN[ic];
          float s0 = ldv(rE,72);
          float s1a[3];
          #pragma unroll
          for (int m = 0; m < 3; ++m) s1a[m] = ldv(rE, 73+m);
          float s2a[5];
          #pragma unroll
          for (int m = 0; m < 5; ++m) s2a[m] = ldv(rE, 76+m);
          float rb0k = ldv(rE, k16) * w;
          float rb1k = ldv(rE, 32+k16) * w;
          float rb2k = ldv(rE, 56+k16) * w;
          float ek   = ldv(rN, k16);
          float f2k[5];
          #pragma unroll
          for (int b = 0; b < 5; ++b) f2k[b] = ldv(rN, 136 + b*16 + k16);
          float re = rb2k * ek;
          #pragma unroll
          for (int m = 0; m < 5; ++m) acc[m] = fmaf(s2a[m], re, acc[m]);
          float ve0 = s0 * rb0k;
          #pragma unroll
          for (int b = 0; b < 5; ++b) acc[5+b] = fmaf(ve0, f2k[b], acc[5+b]);
          #pragma unroll
          for (int aa = 0; aa < 3; ++aa) {
            float sa = rb1k * s1a[aa];
            #pragma unroll
            for (int b = 0; b < 5; ++b)
              acc[10+aa*5+b] = fmaf(sa, f2k[b], acc[10+aa*5+b]);
          }
        }
      }
    } else if (wv == 2) {
      // ---- W2: (2,0,2),(2,1,1),(2,1,2); acc: 0..4=S202[a], 5..19=S21[a*3+b] ----
      for (int base = 0; base < nch; base += 8) {
        #pragma unroll
        for (int u = 0; u < 2; ++u) {
          int idx = base + 4*u + e4;
          float w = (idx < nch) ? 1.f : 0.f;
          int ic  = (idx < nch) ? idx : 0;
          const T* rE = SE[ic];
          const T* rN = SN[ic];
          float s2a[5];
          #pragma unroll
          for (int m = 0; m < 5; ++m) s2a[m] = ldv(rE, 76+m);
          float rb2k = ldv(rE, 56+k16) * w;
          float f0k  = ldv(rN, 32+k16);
          float f1k[3];
          #pragma unroll
          for (int b = 0; b < 3; ++b) f1k[b] = ldv(rN, 64 + b*24 + k16);
          float g9 = rb2k * f0k;
          #pragma unroll
          for (int aa = 0; aa < 5; ++aa) acc[aa] = fmaf(g9, s2a[aa], acc[aa]);
          #pragma unroll
          for (int aa = 0; aa < 5; ++aa) {
            float sa = rb2k * s2a[aa];
            #pragma unroll
            for (int b = 0; b < 3; ++b)
              acc[5+aa*3+b] = fmaf(sa, f1k[b], acc[5+aa*3+b]);
          }
        }
      }
    } else {
      // ---- W3: (2,2,0),(2,2,1),(2,2,2); acc: 0..24=S22[a*5+b] ----
      for (int base = 0; base < nch; base += 8) {
        #pragma unroll
        for (int u = 0; u < 2; ++u) {
          int idx = base + 4*u + e4;
          float w = (idx < nch) ? 1.f : 0.f;
          int ic  = (idx < nch) ? idx : 0;
          const T* rE = SE[ic];
          const T* rN = SN[ic];
          float s2a[5];
          #pragma unroll
          for (int m = 0; m < 5; ++m) s2a[m] = ldv(rE, 76+m);
          float rb2k = ldv(rE, 56+k16) * w;
          float f2k[5];
          #pragma unroll
          for (int b = 0; b < 5; ++b) f2k[b] = ldv(rN, 136 + b*16 + k16);
          #pragma unroll
          for (int aa = 0; aa < 5; ++aa) {
            float sa = rb2k * s2a[aa];
            #pragma unroll
            for (int b = 0; b < 5; ++b)
              acc[aa*5+b] = fmaf(sa, f2k[b], acc[aa*5+b]);
          }
        }
      }
    }
  }

  // ---- cross-lane reductions + per-atom cg contraction ----
  if (wv == 0) {
    #pragma unroll
    for (int i = 0; i < 20; ++i) acc[i] += __shfl_xor(acc[i], 32);
    const float* C000 = cgf + 0;
    const float* C011 = cgf + 1;
    const float* C101 = cgf + 35;
    const float* C110 = cgf + 44;
    const float* C111 = cgf + 53;
    const float* C112 = cgf + 80;
    float r[16];
    r[0] = C000[0] * acc[4];
    #pragma unroll
    for (int M = 0; M < 3; ++M) {
      float t = 0.f;
      #pragma unroll
      for (int b = 0; b < 3; ++b) t = fmaf(acc[5+b], C011[b*3+M], t);
      r[1+M] = t;
    }
    #pragma unroll
    for (int M = 0; M < 3; ++M) {
      float t = 0.f;
      #pragma unroll
      for (int aa = 0; aa < 3; ++aa) t = fmaf(acc[8+aa], C101[aa*3+M], t);
      r[4+M] = t;
    }
    {
      float t = 0.f;
      #pragma unroll
      for (int q = 0; q < 9; ++q) t = fmaf(acc[11+q], C110[q], t);
      r[7] = t;
    }
    #pragma unroll
    for (int M = 0; M < 3; ++M) {
      float t = 0.f;
      #pragma unroll
      for (int q = 0; q < 9; ++q) t = fmaf(acc[11+q], C111[q*3+M], t);
      r[8+M] = t;
    }
    #pragma unroll
    for (int M = 0; M < 5; ++M) {
      float t = 0.f;
      #pragma unroll
      for (int q = 0; q < 9; ++q) t = fmaf(acc[11+q], C112[q*5+M], t);
      r[11+M] = t;
    }
    acc[4] = r[0];
    #pragma unroll
    for (int M = 0; M < 3; ++M) acc[5+M]  = r[1+M];
    #pragma unroll
    for (int M = 0; M < 3; ++M) acc[8+M]  = r[4+M];
    acc[11] = r[7];
    #pragma unroll
    for (int M = 0; M < 3; ++M) acc[12+M] = r[8+M];
    #pragma unroll
    for (int M = 0; M < 5; ++M) acc[15+M] = r[11+M];
  } else if (wv == 1) {
    #pragma unroll
    for (int i = 0; i < 25; ++i) {
      acc[i] += __shfl_xor(acc[i], 16);
      acc[i] += __shfl_xor(acc[i], 32);
    }
    const float* C022 = cgf + 10;
    const float* C121 = cgf + 125;
    const float* C122 = cgf + 170;
    float r[13];
    #pragma unroll
    for (int M = 0; M < 5; ++M) {
      float t = 0.f;
      #pragma unroll
      for (int b = 0; b < 5; ++b) t = fmaf(acc[5+b], C022[b*5+M], t);
      r[M] = t;
    }
    #pragma unroll
    for (int M = 0; M < 3; ++M) {
      float t = 0.f;
      #pragma unroll
      for (int q = 0; q < 15; ++q) t = fmaf(acc[10+q], C121[q*3+M], t);
      r[5+M] = t;
    }
    #pragma unroll
    for (int M = 0; M < 5; ++M) {
      float t = 0.f;
      #pragma unroll
      for (int q = 0; q < 15; ++q) t = fmaf(acc[10+q], C122[q*5+M], t);
      r[8+M] = t;
    }
    #pragma unroll
    for (int M = 0; M < 5; ++M) acc[5+M]  = r[M];
    #pragma unroll
    for (int M = 0; M < 3; ++M) acc[10+M] = r[5+M];
    #pragma unroll
    for (int M = 0; M < 5; ++M) acc[13+M] = r[8+M];
  } else if (wv == 2) {
    #pragma unroll
    for (int i = 0; i < 20; ++i) {
      acc[i] += __shfl_xor(acc[i], 16);
      acc[i] += __shfl_xor(acc[i], 32);
    }
    const float* C202 = cgf + 245;
    const float* C211 = cgf + 270;
    const float* C212 = cgf + 315;
    float r[13];
    #pragma unroll
    for (int M = 0; M < 5; ++M) {
      float t = 0.f;
      #pragma unroll
      for (int aa = 0; aa < 5; ++aa) t = fmaf(acc[aa], C202[aa*5+M], t);
      r[M] = t;
    }
    #pragma unroll
    for (int M = 0; M < 3; ++M) {
      float t = 0.f;
      #pragma unroll
      for (int q = 0; q < 15; ++q) t = fmaf(acc[5+q], C211[q*3+M], t);
      r[5+M] = t;
    }
    #pragma unroll
    for (int M = 0; M < 5; ++M) {
      float t = 0.f;
      #pragma unroll
      for (int q = 0; q < 15; ++q) t = fmaf(acc[5+q], C212[q*5+M], t);
      r[8+M] = t;
    }
    #pragma unroll
    for (int M = 0; M < 5; ++M) acc[M]   = r[M];
    #pragma unroll
    for (int M = 0; M < 3; ++M) acc[5+M] = r[5+M];
    #pragma unroll
    for (int M = 0; M < 5; ++M) acc[8+M] = r[8+M];
  } else {
    #pragma unroll
    for (int i = 0; i < 25; ++i) {
      acc[i] += __shfl_xor(acc[i], 16);
      acc[i] += __shfl_xor(acc[i], 32);
    }
    const float* C220 = cgf + 390;
    const float* C221 = cgf + 415;
    const float* C222 = cgf + 490;
    float r[9];
    {
      float t = 0.f;
      #pragma unroll
      for (int q = 0; q < 25; ++q) t = fmaf(acc[q], C220[q], t);
      r[0] = t;
    }
    #pragma unroll
    for (int M = 0; M < 3; ++M) {
      float t = 0.f;
      #pragma unroll
      for (int q = 0; q < 25; ++q) t = fmaf(acc[q], C221[q*3+M], t);
      r[1+M] = t;
    }
    #pragma unroll
    for (int M = 0; M < 5; ++M) {
      float t = 0.f;
      #pragma unroll
      for (int q = 0; q < 25; ++q) t = fmaf(acc[q], C222[q*5+M], t);
      r[4+M] = t;
    }
    #pragma unroll
    for (int i = 0; i < 9; ++i) acc[i] = r[i];
  }

  // ---------------- epilogues ----------------
  if constexpr (MODE != 2) {
    if (wv == 0) {
      if (lane < 32) {
        stv(out, O0 + a*32 + k32, acc[0]);
        atomicAdd(&s1p[(0+k32)*64+ab], acc[4]*acc[4]);
        if (k32 < 24) {
          #pragma unroll
          for (int m = 0; m < 3; ++m) stv(out, O1 + a*72 + m*24 + k32, acc[1+m]);
          atomicAdd(&s1p[(32+k32)*64+ab], acc[11]*acc[11]);
          float q;
          q = acc[5]*acc[5]+acc[6]*acc[6]+acc[7]*acc[7];
          atomicAdd(&s1p[(72+k32)*64+ab], q);
          q = acc[8]*acc[8]+acc[9]*acc[9]+acc[10]*acc[10];
          atomicAdd(&s1p[(96+k32)*64+ab], q);
          q = acc[12]*acc[12]+acc[13]*acc[13]+acc[14]*acc[14];
          atomicAdd(&s1p[(152+k32)*64+ab], q);
          q = acc[15]*acc[15]+acc[16]*acc[16]+acc[17]*acc[17]
            + acc[18]*acc[18]+acc[19]*acc[19];
          atomicAdd(&s1p[(208+k32)*64+ab], q);
        }
      }
    } else if (wv == 1) {
      if (lane < 16) {
        #pragma unroll
        for (int m = 0; m < 5; ++m) stv(out, O2 + a*80 + m*16 + k16, acc[m]);
        float q;
        q = acc[5]*acc[5]+acc[6]*acc[6]+acc[7]*acc[7]+acc[8]*acc[8]+acc[9]*acc[9];
        atomicAdd(&s1p[(192+k16)*64+ab], q);
        q = acc[10]*acc[10]+acc[11]*acc[11]+acc[12]*acc[12];
        atomicAdd(&s1p[(120+k16)*64+ab], q);
        q = acc[13]*acc[13]+acc[14]*acc[14]+acc[15]*acc[15]
          + acc[16]*acc[16]+acc[17]*acc[17];
        atomicAdd(&s1p[(264+k16)*64+ab], q);
      }
    } else if (wv == 2) {
      if (lane < 16) {
        float q;
        q = acc[0]*acc[0]+acc[1]*acc[1]+acc[2]*acc[2]+acc[3]*acc[3]+acc[4]*acc[4];
        atomicAdd(&s1p[(232+k16)*64+ab], q);
        q = acc[5]*acc[5]+acc[6]*acc[6]+acc[7]*acc[7];
        atomicAdd(&s1p[(136+k16)*64+ab], q);
        q = acc[8]*acc[8]+acc[9]*acc[9]+acc[10]*acc[10]
          + acc[11]*acc[11]+acc[12]*acc[12];
        atomicAdd(&s1p[(280+k16)*64+ab], q);
      }
    } else {
      if (lane < 16) {
        atomicAdd(&s1p[(56+k16)*64+ab], acc[0]*acc[0]);
        float q;
        q = acc[1]*acc[1]+acc[2]*acc[2]+acc[3]*acc[3];
        atomicAdd(&s1p[(176+k16)*64+ab], q);
        q = acc[4]*acc[4]+acc[5]*acc[5]+acc[6]*acc[6]
          + acc[7]*acc[7]+acc[8]*acc[8];
        atomicAdd(&s1p[(248+k16)*64+ab], q);
      }
    }
  }

  if constexpr (MODE == 0) {
    // deposit x into LDS, then stream contiguous float4 (full-line writes)
    if (wv == 0) {
      if (lane < 32) {
        L[k32] = acc[4];
        if (k32 < 24) {
          L[32+k32] = acc[11];
          #pragma unroll
          for (int M = 0; M < 3; ++M) L[72+M*80+k32]     = acc[5+M];
          #pragma unroll
          for (int M = 0; M < 3; ++M) L[72+M*80+24+k32]  = acc[8+M];
          #pragma unroll
          for (int M = 0; M < 3; ++M) L[312+M*40+k32]    = acc[12+M];
          #pragma unroll
          for (int M = 0; M < 5; ++M) L[432+M*72+16+k32] = acc[15+M];
        }
      }
    } else if (wv == 1) {
      if (lane < 16) {
        #pragma unroll
        for (int M = 0; M < 5; ++M) L[432+M*72+k16]    = acc[5+M];
        #pragma unroll
        for (int M = 0; M < 3; ++M) L[72+M*80+48+k16]  = acc[10+M];
        #pragma unroll
        for (int M = 0; M < 5; ++M) L[792+M*32+k16]    = acc[13+M];
      }
    } else if (wv == 2) {
      if (lane < 16) {
        #pragma unroll
        for (int M = 0; M < 5; ++M) L[432+M*72+40+k16] = acc[0+M];
        #pragma unroll
        for (int M = 0; M < 3; ++M) L[72+M*80+64+k16]  = acc[5+M];
        #pragma unroll
        for (int M = 0; M < 5; ++M) L[792+M*32+16+k16] = acc[8+M];
      }
    } else {
      if (lane < 16) {
        L[56+k16] = acc[0];
        #pragma unroll
        for (int M = 0; M < 3; ++M) L[312+M*40+24+k16] = acc[1+M];
        #pragma unroll
        for (int M = 0; M < 5; ++M) L[432+M*72+56+k16] = acc[4+M];
      }
    }
    __syncthreads();
    const float4* Ls = (const float4*)L;
    float4* xd = (float4*)(xout + a*952);
    for (int i = tix; i < 238; i += 256) xd[i] = Ls[i];
  }

  if constexpr (MODE == 2) {
    if (wv == 0) {
      if (lane < 32) {
        L[k32] = acc[4]*inv[k32];
        if (k32 < 24) {
          L[32+k32] = acc[11]*inv[32+k32];
          #pragma unroll
          for (int M = 0; M < 3; ++M) L[72+M*80+k32]     = acc[5+M]*inv[72+k32];
          #pragma unroll
          for (int M = 0; M < 3; ++M) L[72+M*80+24+k32]  = acc[8+M]*inv[96+k32];
          #pragma unroll
          for (int M = 0; M < 3; ++M) L[312+M*40+k32]    = acc[12+M]*inv[152+k32];
          #pragma unroll
          for (int M = 0; M < 5; ++M) L[432+M*72+16+k32] = acc[15+M]*inv[208+k32];
        }
      }
    } else if (wv == 1) {
      if (lane < 16) {
        #pragma unroll
        for (int M = 0; M < 5; ++M) L[432+M*72+k16]    = acc[5+M]*inv[192+k16];
        #pragma unroll
        for (int M = 0; M < 3; ++M) L[72+M*80+48+k16]  = acc[10+M]*inv[120+k16];
        #pragma unroll
        for (int M = 0; M < 5; ++M) L[792+M*32+k16]    = acc[13+M]*inv[264+k16];
      }
    } else if (wv == 2) {
      if (lane < 16) {
        #pragma unroll
        for (int M = 0; M < 5; ++M) L[432+M*72+40+k16] = acc[0+M]*inv[232+k16];
        #pragma unroll
        for (int M = 0; M < 3; ++M) L[72+M*80+64+k16]  = acc[5+M]*inv[136+k16];
        #pragma unroll
        for (int M = 0; M < 5; ++M) L[792+M*32+16+k16] = acc[8+M]*inv[280+k16];
      }
    } else {
      if (lane < 16) {
        L[56+k16] = acc[0]*inv[56+k16];
        #pragma unroll
        for (int M = 0; M < 3; ++M) L[312+M*40+24+k16] = acc[1+M]*inv[176+k16];
        #pragma unroll
        for (int M = 0; M < 5; ++M) L[432+M*72+56+k16] = acc[4+M]*inv[248+k16];
      }
    }
    __syncthreads();
    int t = threadIdx.x;
    float y2[5] = {0.f,0.f,0.f,0.f,0.f};
    for (int tau = t; tau < 336; tau += 256) {
      int ls = 0;
      while (tau >= c_cum[ls+1]) ++ls;
      int rem = tau - c_cum[ls];
      int kn = c_kout[ls], fin = c_fin[ls];
      int M = rem / kn, ko = rem - M*kn;
      const T* W = (const T*)lp.W[ls];
      float y = ldv((const T*)lp.B[ls], ko);
      const float* xv = &L[c_xb[ls] + M*fin];
      for (int f = 0; f < fin; ++f) y = fmaf(xv[f], ldv(W, f*kn+ko), y);
      stv(out, c_yoff[ls] + (a*c_Ms[ls] + M)*kn + ko, y);
      y2[ls] += y*y;
    }
    #pragma unroll
    for (int i = 0; i < 5; ++i) {
      y2[i] += __shfl_xor(y2[i], 1);  y2[i] += __shfl_xor(y2[i], 2);
      y2[i] += __shfl_xor(y2[i], 4);  y2[i] += __shfl_xor(y2[i], 8);
      y2[i] += __shfl_xor(y2[i], 16); y2[i] += __shfl_xor(y2[i], 32);
    }
    if (lane == 0) {
      #pragma unroll
      for (int i = 0; i < 5; ++i) red[wv][i] = y2[i];
    }
    __syncthreads();
    if (t == 0) {
      #pragma unroll
      for (int i = 0; i < 5; ++i)
        atomicAdd(&s2p[i*64 + ab], red[0][i]+red[1][i]+red[2][i]+red[3][i]);
    }
  }
}

// ---------------- big path: normalize + linear from stored x ----------------
template<typename T>
__global__ __launch_bounds__(256) void k_lin(
    const float* __restrict__ xg, const float* __restrict__ inv,
    LinP lp, T* __restrict__ out, float* __restrict__ s2p,
    const int* __restrict__ flag)
{
  if (flag[0] != dtid<T>()) return;
  int a = blockIdx.x;
  int t = threadIdx.x;
  __shared__ float L[952];
  for (int i = t; i < 952; i += 256) {
    int ch;
    if      (i < 72)  ch = i;
    else if (i < 312) ch = 72  + (i-72)  % 80;
    else if (i < 432) ch = 152 + (i-312) % 40;
    else if (i < 792) ch = 192 + (i-432) % 72;
    else              ch = 264 + (i-792) % 32;
    L[i] = xg[a*952 + i] * inv[ch];
  }
  __syncthreads();
  float y2[5] = {0.f,0.f,0.f,0.f,0.f};
  for (int tau = t; tau < 336; tau += 256) {
    int ls = 0;
    while (tau >= c_cum[ls+1]) ++ls;
    int rem = tau - c_cum[ls];
    int kn = c_kout[ls], fin = c_fin[ls];
    int M = rem / kn, ko = rem - M*kn;
    const T* W = (const T*)lp.W[ls];
    float y = ldv((const T*)lp.B[ls], ko);
    const float* xv = &L[c_xb[ls] + M*fin];
    for (int f = 0; f < fin; ++f) y = fmaf(xv[f], ldv(W, f*kn+ko), y);
    stv(out, c_yoff[ls] + (a*c_Ms[ls] + M)*kn + ko, y);
    y2[ls] += y*y;
  }
  __shared__ float red[4][5];
  #pragma unroll
  for (int i = 0; i < 5; ++i) {
    y2[i] += __shfl_xor(y2[i], 1);  y2[i] += __shfl_xor(y2[i], 2);
    y2[i] += __shfl_xor(y2[i], 4);  y2[i] += __shfl_xor(y2[i], 8);
    y2[i] += __shfl_xor(y2[i], 16); y2[i] += __shfl_xor(y2[i], 32);
  }
  if ((t & 63) == 0) {
    #pragma unroll
    for (int i = 0; i < 5; ++i) red[t>>6][i] = y2[i];
  }
  __syncthreads();
  if (t == 0) {
    #pragma unroll
    for (int i = 0; i < 5; ++i)
      atomicAdd(&s2p[i*64 + (a & 63)], red[0][i]+red[1][i]+red[2][i]+red[3][i]);
  }
}

// ---------------- reducers ----------------
__global__ void k_red1(const float* __restrict__ s1p, float* __restrict__ inv) {
  int ch = blockIdx.x, lane = threadIdx.x;
  float v = s1p[ch*64 + lane];
  v += __shfl_xor(v, 1);  v += __shfl_xor(v, 2);  v += __shfl_xor(v, 4);
  v += __shfl_xor(v, 8);  v += __shfl_xor(v, 16); v += __shfl_xor(v, 32);
  if (lane == 0) {
    float rows = (ch < 72) ? 10000.f : (ch < 192) ? 30000.f : 50000.f;
    inv[ch] = rsqrtf(v/rows + 1e-12f);
  }
}

__global__ void k_red2(const float* __restrict__ s2p, float* __restrict__ ws2) {
  int ls = blockIdx.x, lane = threadIdx.x;
  float v = s2p[ls*64 + lane];
  v += __shfl_xor(v, 1);  v += __shfl_xor(v, 2);  v += __shfl_xor(v, 4);
  v += __shfl_xor(v, 8);  v += __shfl_xor(v, 16); v += __shfl_xor(v, 32);
  if (lane == 0) ws2[ls] = v;
}

// ---------------- final global RMS scale, in place ----------------
template<typename T>
__global__ void k_scale(const float* __restrict__ ws2, T* __restrict__ out,
                        const int* __restrict__ flag) {
  if (flag[0] != dtid<T>()) return;
  int i = blockIdx.x*blockDim.x + threadIdx.x;
  if (i >= 3360000) return;
  int ls = (i < 320000) ? 0 : (i < 1040000) ? 1 : (i < 1760000) ? 2 : (i < 2560000) ? 3 : 4;
  float scale = rsqrtf(ws2[ls] / (float)c_numel[ls] + 1e-12f);
  stv(out, OY + i, ldv((const T*)out, OY + i) * scale);
}

template<typename T>
static void launch_chain(void* const* d_in, T* out, float* wsf, int* wsi,
                         Ptrs15 cg, LinP lp, bool big, hipStream_t stream) {
  const T* rb0 = (const T*)d_in[0];
  const T* rb1 = (const T*)d_in[1];
  const T* rb2 = (const T*)d_in[2];
  const T* sh0 = (const T*)d_in[3];
  const T* sh1 = (const T*)d_in[4];
  const T* sh2 = (const T*)d_in[5];
  const T* emb = (const T*)d_in[6];
  const T* f0  = (const T*)d_in[7];
  const T* f1  = (const T*)d_in[8];
  const T* f2  = (const T*)d_in[9];
  const int* neighbors = (const int*)d_in[36];
  const int* flag = wsi + IFLAG;

  k_cg<T><<<3, 256, 0, stream>>>(cg, wsf, flag);
  if (big) {
    k_main<T,0><<<N_ATOMS, 256, 0, stream>>>(rb0, rb1, rb2, sh0, sh1, sh2, emb, f0, f1, f2,
        neighbors, wsi+IOFFS, wsi+IELIST, wsf+SCG, wsf+SS1P, nullptr, nullptr,
        wsf+SXACC, lp, out, flag);
    k_red1<<<296, 64, 0, stream>>>(wsf+SS1P, wsf+SINV);
    k_lin<T><<<N_ATOMS, 256, 0, stream>>>(wsf+SXACC, wsf+SINV, lp, out, wsf+SS2P, flag);
  } else {
    k_main<T,1><<<N_ATOMS, 256, 0, stream>>>(rb0, rb1, rb2, sh0, sh1, sh2, emb, f0, f1, f2,
        neighbors, wsi+IOFFS, wsi+IELIST, wsf+SCG, wsf+SS1P, nullptr, nullptr,
        nullptr, lp, out, flag);
    k_red1<<<296, 64, 0, stream>>>(wsf+SS1P, wsf+SINV);
    k_main<T,2><<<N_ATOMS, 256, 0, stream>>>(rb0, rb1, rb2, sh0, sh1, sh2, emb, f0, f1, f2,
        neighbors, wsi+IOFFS, wsi+IELIST, wsf+SCG, nullptr, wsf+SINV, wsf+SS2P,
        nullptr, lp, out, flag);
  }
  k_red2<<<5, 64, 0, stream>>>(wsf+SS2P, wsf+SWS2);
  k_scale<T><<<(3360000+255)/256, 256, 0, stream>>>(wsf+SWS2, out, flag);
}

extern "C" void kernel_launch(void* const* d_in, const int* in_sizes, int n_in,
                              void* d_out, int out_size, void* d_ws, size_t ws_size,
                              hipStream_t stream) {
  float* wsf = (float*)d_ws;
  int*   wsi = (int*)(wsf + SINTS);
  const int* centers   = (const int*)d_in[35];
  bool big = ws_size >= (size_t)BIG_FLOATS * 4;

  // Host-side dtype detection.
  // know: 0 = bf16 only, 1 = fp32 only, -1 = ambiguous -> dual chain + probe.
  int know = -1;
  if (in_sizes) {
    long long nb = (long long)in_sizes[0];         // rb0: 200000*32 elems
    if (nb == (long long)N_EDGES*32*2) know = 0;
    else if (nb == (long long)N_EDGES*32*4) know = 1;
  }
  if (know < 0) {
    long long ob = (long long)out_size;            // 5.2M output elems
    if (ob == (long long)OUT_ELEMS*2) know = 0;
    else if (ob == (long long)OUT_ELEMS*4) know = 1;
  }

  Ptrs15 cg;
  for (int i = 0; i < 15; ++i) cg.p[i] = d_in[10+i];
  LinP lp;
  lp.W[0] = d_in[25]; lp.B[0] = d_in[26];
  lp.W[1] = d_in[27]; lp.B[1] = d_in[28];
  lp.W[2] = d_in[29]; lp.B[2] = d_in[30];
  lp.W[3] = d_in[31]; lp.B[3] = d_in[32];
  lp.W[4] = d_in[33]; lp.B[4] = d_in[34];

  k_zero<<<154, 256, 0, stream>>>(wsf, wsi,
                                  (const unsigned short*)d_in[0],
                                  (const unsigned short*)d_in[6]);
  k_hist<<<(N_EDGES+255)/256, 256, 0, stream>>>(centers, wsi+ICOUNT);
  k_scan<<<1, 1024, 0, stream>>>(wsi+ICOUNT, wsi+IOFFS);
  k_scatter<<<(N_EDGES+255)/256, 256, 0, stream>>>(centers, wsi+IOFFS, wsi+ICURS, wsi+IELIST);

  if (know != 1) launch_chain<bf16 >(d_in, (bf16*)d_out,  wsf, wsi, cg, lp, big, stream);
  if (know != 0) launch_chain<float>(d_in, (float*)d_out, wsf, wsi, cg, lp, big, stream);
}

// Round 5
// 450.281 us; speedup vs baseline: 1.6784x; 1.1478x over previous
//
#include <hip/hip_runtime.h>
#include <hip/hip_bf16.h>

typedef __hip_bfloat16 bf16;

#define N_ATOMS 10000
#define N_EDGES 200000

// ======== float region of ws (float offsets) ========
#define SCG   0        // 615 cg coeffs f32
#define SINV  616      // 296 inv per channel (+pad)
#define SS1P  1024     // 64*296 partials [ab][ch]
#define SS2P  19968    // 5*64 partials
#define SWS2  20288    // 5 (+pad)
#define SINTS 20352    // int region starts here (float idx)
// ======== int region (offsets in ints, relative to SINTS) ========
#define IFLAG  0
#define ICOUNT 16      // 10000
#define IOFFS  10016   // 10001 (+pad)
#define ICURS  20032   // 10000
#define IELIST 30032   // 400000 ints (int2 records)
#define INTS_END 430032
#define SXACC (SINTS + INTS_END)
#define BIG_FLOATS (SXACC + 952*N_ATOMS)      // ~39.9 MB

// ---- d_out element offsets ----
#define O0 0
#define O1 320000
#define O2 1040000
#define OY 1840000
#define OUT_ELEMS 5200000

__device__ __forceinline__ float b2f(bf16 x){ return __bfloat162float(x); }
__device__ __forceinline__ bf16  f2b(float x){ return __float2bfloat16(x); }

__device__ __forceinline__ float ldv(const float* p, int i){ return p[i]; }
__device__ __forceinline__ float ldv(const bf16*  p, int i){ return b2f(p[i]); }
__device__ __forceinline__ void  stv(float* p, int i, float v){ p[i] = v; }
__device__ __forceinline__ void  stv(bf16*  p, int i, float v){ p[i] = f2b(v); }

template<typename T> __device__ __forceinline__ int dtid();
template<> __device__ __forceinline__ int dtid<bf16>(){ return 0; }
template<> __device__ __forceinline__ int dtid<float>(){ return 1; }

struct Ptrs15 { const void* p[15]; };
struct LinP   { const void* W[5]; const void* B[5]; };

__constant__ int c_cg_sizes[15] = {1,9,25,9,9,27,45,45,75,25,45,75,25,75,125};
__constant__ int c_fin[5]   = {72,80,40,72,32};
__constant__ int c_kout[5]  = {32,24,24,16,16};
__constant__ int c_yoff[5]  = {OY+0, OY+320000, OY+1040000, OY+1760000, OY+2560000};
__constant__ int c_numel[5] = {320000,720000,720000,800000,800000};
__constant__ int c_cum[6]   = {0,32,104,176,256,336};
__constant__ int c_xb[5]    = {0,72,312,432,792};
__constant__ int c_Ms[5]    = {1,3,3,5,5};

// ---------------- zero + dtype probe (fallback path) ----------------
__global__ void k_zero(float* wsf, int* wsi,
                       const unsigned short* rb0u, const unsigned short* embu) {
  if (blockIdx.x == 0 && threadIdx.x < 64) {
    int lane = threadIdx.x;
    int bad = 0;
    for (int i = lane; i < 256; i += 64) {
      unsigned u1 = ((unsigned)rb0u[2*i]) << 16;
      unsigned u2 = ((unsigned)embu[2*i]) << 16;
      float v1 = __uint_as_float(u1);
      float v2 = __uint_as_float(u2);
      if (!(fabsf(v1) < 1e9f) || !(fabsf(v2) < 1e9f)) bad = 1;
    }
    unsigned long long any = __ballot(bad);
    if (lane == 0) wsi[IFLAG] = (any != 0ULL) ? 1 : 0;   // 1 = fp32, 0 = bf16
  }
  int i = blockIdx.x*blockDim.x + threadIdx.x;
  if (i < N_ATOMS) wsi[ICOUNT + i] = 0;
  int j = i - N_ATOMS;
  if (j >= 0 && j < N_ATOMS) wsi[ICURS + j] = 0;
  j -= N_ATOMS;
  if (j >= 0 && j < 18944) wsf[SS1P + j] = 0.f;
  j -= 18944;
  if (j >= 0 && j < 325) wsf[SS2P + j] = 0.f;
}

template<typename T>
__global__ void k_cg(Ptrs15 cg, float* wsf, const int* flag) {
  if (flag[0] != dtid<T>()) return;
  int i = blockIdx.x*blockDim.x + threadIdx.x;
  if (i >= 615) return;
  int s = 0, off = i;
  while (off >= c_cg_sizes[s]) { off -= c_cg_sizes[s]; ++s; }
  wsf[SCG + i] = ldv((const T*)cg.p[s], off);
}

__global__ void k_hist(const int* __restrict__ centers, int* __restrict__ counts) {
  int e = blockIdx.x*blockDim.x + threadIdx.x;
  if (e < N_EDGES) atomicAdd(&counts[centers[e]], 1);
}

__global__ void k_scan(const int* __restrict__ counts, int* __restrict__ offs) {
  __shared__ int part[1024];
  int t = threadIdx.x;
  int base = t*10;
  int s = 0;
  for (int i = 0; i < 10; ++i) { int idx = base+i; if (idx < N_ATOMS) s += counts[idx]; }
  part[t] = s;
  __syncthreads();
  for (int d = 1; d < 1024; d <<= 1) {
    int v = part[t];
    int add = (t >= d) ? part[t-d] : 0;
    __syncthreads();
    part[t] = v + add;
    __syncthreads();
  }
  int run = (t == 0) ? 0 : part[t-1];
  for (int i = 0; i < 10; ++i) {
    int idx = base+i;
    if (idx < N_ATOMS) { offs[idx] = run; run += counts[idx]; }
  }
  if (t == 1023) offs[N_ATOMS] = part[1023];
}

__global__ void k_scatter2(const int* __restrict__ centers, const int* __restrict__ neighbors,
                           const int* __restrict__ offs, int* __restrict__ cursors,
                           int2* __restrict__ elist2) {
  int e = blockIdx.x*blockDim.x + threadIdx.x;
  if (e < N_EDGES) {
    int c = centers[e];
    int p = atomicAdd(&cursors[c], 1);
    elist2[offs[c] + p] = make_int2(e, neighbors[e]);
  }
}

// ---------------- role kernel (big path) ----------------------------------
// 5 independent work-items per atom, one wave each, 2 waves per 128-thread
// block, NO LDS, NO barriers. Light roles retire early; up to ~28 independent
// gather streams per CU hide L2/L3 latency. Adjacent blocks share the atom ->
// L2 reuse across roles. s1p layout [ab*296+ch] (wave-atomic = 1-2 lines).
// role 0: d0,d1 + x000,x011      role 1: x110,x101,x111,x112
// role 2: d2 + x022,x121,x122    role 3: x202,x211,x212    role 4: x220,x221,x222
template<typename T>
__global__ __launch_bounds__(128) void k_role(
    const T* __restrict__ rb0, const T* __restrict__ rb1, const T* __restrict__ rb2,
    const T* __restrict__ sh0, const T* __restrict__ sh1, const T* __restrict__ sh2,
    const T* __restrict__ emb, const T* __restrict__ f0, const T* __restrict__ f1,
    const T* __restrict__ f2, const int2* __restrict__ el2,
    const int* __restrict__ offs, const float* __restrict__ cgf,
    float* __restrict__ s1p, float* __restrict__ xout, T* __restrict__ out,
    const int* __restrict__ flag)
{
  if (flag[0] != dtid<T>()) return;
  int lane = threadIdx.x & 63;
  int g = blockIdx.x * 2 + (threadIdx.x >> 6);   // 0..49999
  int a = g / 5;
  int role = g - a*5;
  int beg = offs[a];
  int cnt = offs[a+1] - beg;
  const int2* eb = el2 + beg;
  int ab = a & 63;
  int k32 = lane & 31, e2 = lane >> 5;
  int k16 = lane & 15, e4 = lane >> 4;
  float* xg = xout + a*952;
  float* s1r = s1p + ab*296;

  if (role == 0) {
    // d0, d1, S000, S011 — lanes (e2,k32), 4 edges in flight
    float acc[8];
    #pragma unroll
    for (int i = 0; i < 8; ++i) acc[i] = 0.f;
    for (int base = 0; base < cnt; base += 4) {
      #pragma unroll
      for (int u = 0; u < 2; ++u) {
        int idx = base + 2*u + e2;
        float w = (idx < cnt) ? 1.f : 0.f;
        int ic  = (idx < cnt) ? idx : 0;
        int2 en = eb[ic];
        int e = en.x, n = en.y;
        float s0 = ldv(sh0, e);
        float s1a0 = ldv(sh1, e*3+0), s1a1 = ldv(sh1, e*3+1), s1a2 = ldv(sh1, e*3+2);
        float rb0k = ldv(rb0, e*32 + k32) * w;
        float ek   = ldv(emb, n*32 + k32);
        float f0k  = ldv(f0,  n*32 + k32);
        float ve0 = s0 * rb0k;
        acc[0] = fmaf(ve0, ek, acc[0]);
        acc[4] = fmaf(ve0, f0k, acc[4]);
        if (k32 < 24) {
          float rb1k = ldv(rb1, e*24 + k32) * w;
          float rbek = rb1k * ek;
          acc[1] = fmaf(s1a0, rbek, acc[1]);
          acc[2] = fmaf(s1a1, rbek, acc[2]);
          acc[3] = fmaf(s1a2, rbek, acc[3]);
          float f1k0 = ldv(f1, n*72 + k32);
          float f1k1 = ldv(f1, n*72 + 24 + k32);
          float f1k2 = ldv(f1, n*72 + 48 + k32);
          acc[5] = fmaf(ve0, f1k0, acc[5]);
          acc[6] = fmaf(ve0, f1k1, acc[6]);
          acc[7] = fmaf(ve0, f1k2, acc[7]);
        }
      }
    }
    #pragma unroll
    for (int i = 0; i < 8; ++i) acc[i] += __shfl_xor(acc[i], 32);
    float x000 = cgf[0] * acc[4];
    const float* C011 = cgf + 1;
    float x011[3];
    #pragma unroll
    for (int M = 0; M < 3; ++M) {
      float t = 0.f;
      #pragma unroll
      for (int b = 0; b < 3; ++b) t = fmaf(acc[5+b], C011[b*3+M], t);
      x011[M] = t;
    }
    if (lane < 32) {
      stv(out, O0 + a*32 + k32, acc[0]);
      xg[k32] = x000;
      atomicAdd(&s1r[k32], x000*x000);
      if (k32 < 24) {
        #pragma unroll
        for (int m = 0; m < 3; ++m) stv(out, O1 + a*72 + m*24 + k32, acc[1+m]);
        #pragma unroll
        for (int M = 0; M < 3; ++M) xg[72+M*80+k32] = x011[M];
        atomicAdd(&s1r[72+k32], x011[0]*x011[0]+x011[1]*x011[1]+x011[2]*x011[2]);
      }
    }
  } else if (role == 1) {
    // S101, S11 — lanes (e2,k32) with k<24 masked
    float acc[12];
    #pragma unroll
    for (int i = 0; i < 12; ++i) acc[i] = 0.f;
    int k24 = (k32 < 24) ? k32 : 23;
    float m24 = (k32 < 24) ? 1.f : 0.f;
    for (int base = 0; base < cnt; base += 4) {
      #pragma unroll
      for (int u = 0; u < 2; ++u) {
        int idx = base + 2*u + e2;
        float w = ((idx < cnt) ? 1.f : 0.f) * m24;
        int ic  = (idx < cnt) ? idx : 0;
        int2 en = eb[ic];
        int e = en.x, n = en.y;
        float s1a0 = ldv(sh1, e*3+0), s1a1 = ldv(sh1, e*3+1), s1a2 = ldv(sh1, e*3+2);
        float rb1k = ldv(rb1, e*24 + k24) * w;
        float f0k  = ldv(f0,  n*32 + k24);
        float f1k0 = ldv(f1, n*72 + k24);
        float f1k1 = ldv(f1, n*72 + 24 + k24);
        float f1k2 = ldv(f1, n*72 + 48 + k24);
        float g3 = rb1k * f0k;
        acc[0] = fmaf(g3, s1a0, acc[0]);
        acc[1] = fmaf(g3, s1a1, acc[1]);
        acc[2] = fmaf(g3, s1a2, acc[2]);
        float sa;
        sa = rb1k * s1a0;
        acc[3] = fmaf(sa, f1k0, acc[3]); acc[4] = fmaf(sa, f1k1, acc[4]); acc[5] = fmaf(sa, f1k2, acc[5]);
        sa = rb1k * s1a1;
        acc[6] = fmaf(sa, f1k0, acc[6]); acc[7] = fmaf(sa, f1k1, acc[7]); acc[8] = fmaf(sa, f1k2, acc[8]);
        sa = rb1k * s1a2;
        acc[9] = fmaf(sa, f1k0, acc[9]); acc[10] = fmaf(sa, f1k1, acc[10]); acc[11] = fmaf(sa, f1k2, acc[11]);
      }
    }
    #pragma unroll
    for (int i = 0; i < 12; ++i) acc[i] += __shfl_xor(acc[i], 32);
    const float* C101 = cgf + 35;
    const float* C110 = cgf + 44;
    const float* C111 = cgf + 53;
    const float* C112 = cgf + 80;
    float x101[3], x111[3], x112[5], x110;
    #pragma unroll
    for (int M = 0; M < 3; ++M) {
      float t = 0.f;
      #pragma unroll
      for (int aa = 0; aa < 3; ++aa) t = fmaf(acc[aa], C101[aa*3+M], t);
      x101[M] = t;
    }
    {
      float t = 0.f;
      #pragma unroll
      for (int q = 0; q < 9; ++q) t = fmaf(acc[3+q], C110[q], t);
      x110 = t;
    }
    #pragma unroll
    for (int M = 0; M < 3; ++M) {
      float t = 0.f;
      #pragma unroll
      for (int q = 0; q < 9; ++q) t = fmaf(acc[3+q], C111[q*3+M], t);
      x111[M] = t;
    }
    #pragma unroll
    for (int M = 0; M < 5; ++M) {
      float t = 0.f;
      #pragma unroll
      for (int q = 0; q < 9; ++q) t = fmaf(acc[3+q], C112[q*5+M], t);
      x112[M] = t;
    }
    if (lane < 24) {
      xg[32+k32] = x110;
      #pragma unroll
      for (int M = 0; M < 3; ++M) xg[72+M*80+24+k32] = x101[M];
      #pragma unroll
      for (int M = 0; M < 3; ++M) xg[312+M*40+k32]   = x111[M];
      #pragma unroll
      for (int M = 0; M < 5; ++M) xg[432+M*72+16+k32] = x112[M];
      atomicAdd(&s1r[32+k32], x110*x110);
      atomicAdd(&s1r[96+k32], x101[0]*x101[0]+x101[1]*x101[1]+x101[2]*x101[2]);
      atomicAdd(&s1r[152+k32], x111[0]*x111[0]+x111[1]*x111[1]+x111[2]*x111[2]);
      atomicAdd(&s1r[208+k32], x112[0]*x112[0]+x112[1]*x112[1]+x112[2]*x112[2]
                              + x112[3]*x112[3]+x112[4]*x112[4]);
    }
  } else if (role == 2) {
    // d2, S022, S12 — lanes (e4,k16), 8 edges in flight
    float acc[25];
    #pragma unroll
    for (int i = 0; i < 25; ++i) acc[i] = 0.f;
    for (int base = 0; base < cnt; base += 8) {
      #pragma unroll
      for (int u = 0; u < 2; ++u) {
        int idx = base + 4*u + e4;
        float w = (idx < cnt) ? 1.f : 0.f;
        int ic  = (idx < cnt) ? idx : 0;
        int2 en = eb[ic];
        int e = en.x, n = en.y;
        float s0 = ldv(sh0, e);
        float s1a[3];
        #pragma unroll
        for (int m = 0; m < 3; ++m) s1a[m] = ldv(sh1, e*3+m);
        float s2a[5];
        #pragma unroll
        for (int m = 0; m < 5; ++m) s2a[m] = ldv(sh2, e*5+m);
        float rb0k = ldv(rb0, e*32 + k16) * w;
        float rb1k = ldv(rb1, e*24 + k16) * w;
        float rb2k = ldv(rb2, e*16 + k16) * w;
        float ek   = ldv(emb, n*32 + k16);
        float f2k[5];
        #pragma unroll
        for (int b = 0; b < 5; ++b) f2k[b] = ldv(f2, n*80 + b*16 + k16);
        float re = rb2k * ek;
        #pragma unroll
        for (int m = 0; m < 5; ++m) acc[m] = fmaf(s2a[m], re, acc[m]);
        float ve0 = s0 * rb0k;
        #pragma unroll
        for (int b = 0; b < 5; ++b) acc[5+b] = fmaf(ve0, f2k[b], acc[5+b]);
        #pragma unroll
        for (int aa = 0; aa < 3; ++aa) {
          float sa = rb1k * s1a[aa];
          #pragma unroll
          for (int b = 0; b < 5; ++b)
            acc[10+aa*5+b] = fmaf(sa, f2k[b], acc[10+aa*5+b]);
        }
      }
    }
    #pragma unroll
    for (int i = 0; i < 25; ++i) {
      acc[i] += __shfl_xor(acc[i], 16);
      acc[i] += __shfl_xor(acc[i], 32);
    }
    const float* C022 = cgf + 10;
    const float* C121 = cgf + 125;
    const float* C122 = cgf + 170;
    float x022[5], x121[3], x122[5];
    #pragma unroll
    for (int M = 0; M < 5; ++M) {
      float t = 0.f;
      #pragma unroll
      for (int b = 0; b < 5; ++b) t = fmaf(acc[5+b], C022[b*5+M], t);
      x022[M] = t;
    }
    #pragma unroll
    for (int M = 0; M < 3; ++M) {
      float t = 0.f;
      #pragma unroll
      for (int q = 0; q < 15; ++q) t = fmaf(acc[10+q], C121[q*3+M], t);
      x121[M] = t;
    }
    #pragma unroll
    for (int M = 0; M < 5; ++M) {
      float t = 0.f;
      #pragma unroll
      for (int q = 0; q < 15; ++q) t = fmaf(acc[10+q], C122[q*5+M], t);
      x122[M] = t;
    }
    if (lane < 16) {
      #pragma unroll
      for (int m = 0; m < 5; ++m) stv(out, O2 + a*80 + m*16 + k16, acc[m]);
      #pragma unroll
      for (int M = 0; M < 5; ++M) xg[432+M*72+k16]   = x022[M];
      #pragma unroll
      for (int M = 0; M < 3; ++M) xg[72+M*80+48+k16] = x121[M];
      #pragma unroll
      for (int M = 0; M < 5; ++M) xg[792+M*32+k16]   = x122[M];
      atomicAdd(&s1r[192+k16], x022[0]*x022[0]+x022[1]*x022[1]+x022[2]*x022[2]
                              + x022[3]*x022[3]+x022[4]*x022[4]);
      atomicAdd(&s1r[120+k16], x121[0]*x121[0]+x121[1]*x121[1]+x121[2]*x121[2]);
      atomicAdd(&s1r[264+k16], x122[0]*x122[0]+x122[1]*x122[1]+x122[2]*x122[2]
                              + x122[3]*x122[3]+x122[4]*x122[4]);
    }
  } else if (role == 3) {
    // S202, S21 — lanes (e4,k16)
    float acc[20];
    #pragma unroll
    for (int i = 0; i < 20; ++i) acc[i] = 0.f;
    for (int base = 0; base < cnt; base += 8) {
      #pragma unroll
      for (int u = 0; u < 2; ++u) {
        int idx = base + 4*u + e4;
        float w = (idx < cnt) ? 1.f : 0.f;
        int ic  = (idx < cnt) ? idx : 0;
        int2 en = eb[ic];
        int e = en.x, n = en.y;
        float s2a[5];
        #pragma unroll
        for (int m = 0; m < 5; ++m) s2a[m] = ldv(sh2, e*5+m);
        float rb2k = ldv(rb2, e*16 + k16) * w;
        float f0k  = ldv(f0,  n*32 + k16);
        float f1k[3];
        #pragma unroll
        for (int b = 0; b < 3; ++b) f1k[b] = ldv(f1, n*72 + b*24 + k16);
        float g9 = rb2k * f0k;
        #pragma unroll
        for (int aa = 0; aa < 5; ++aa) acc[aa] = fmaf(g9, s2a[aa], acc[aa]);
        #pragma unroll
        for (int aa = 0; aa < 5; ++aa) {
          float sa = rb2k * s2a[aa];
          #pragma unroll
          for (int b = 0; b < 3; ++b)
            acc[5+aa*3+b] = fmaf(sa, f1k[b], acc[5+aa*3+b]);
        }
      }
    }
    #pragma unroll
    for (int i = 0; i < 20; ++i) {
      acc[i] += __shfl_xor(acc[i], 16);
      acc[i] += __shfl_xor(acc[i], 32);
    }
    const float* C202 = cgf + 245;
    const float* C211 = cgf + 270;
    const float* C212 = cgf + 315;
    float x202[5], x211[3], x212[5];
    #pragma unroll
    for (int M = 0; M < 5; ++M) {
      float t = 0.f;
      #pragma unroll
      for (int aa = 0; aa < 5; ++aa) t = fmaf(acc[aa], C202[aa*5+M], t);
      x202[M] = t;
    }
    #pragma unroll
    for (int M = 0; M < 3; ++M) {
      float t = 0.f;
      #pragma unroll
      for (int q = 0; q < 15; ++q) t = fmaf(acc[5+q], C211[q*3+M], t);
      x211[M] = t;
    }
    #pragma unroll
    for (int M = 0; M < 5; ++M) {
      float t = 0.f;
      #pragma unroll
      for (int q = 0; q < 15; ++q) t = fmaf(acc[5+q], C212[q*5+M], t);
      x212[M] = t;
    }
    if (lane < 16) {
      #pragma unroll
      for (int M = 0; M < 5; ++M) xg[432+M*72+40+k16] = x202[M];
      #pragma unroll
      for (int M = 0; M < 3; ++M) xg[72+M*80+64+k16]  = x211[M];
      #pragma unroll
      for (int M = 0; M < 5; ++M) xg[792+M*32+16+k16] = x212[M];
      atomicAdd(&s1r[232+k16], x202[0]*x202[0]+x202[1]*x202[1]+x202[2]*x202[2]
                              + x202[3]*x202[3]+x202[4]*x202[4]);
      atomicAdd(&s1r[136+k16], x211[0]*x211[0]+x211[1]*x211[1]+x211[2]*x211[2]);
      atomicAdd(&s1r[280+k16], x212[0]*x212[0]+x212[1]*x212[1]+x212[2]*x212[2]
                              + x212[3]*x212[3]+x212[4]*x212[4]);
    }
  } else {
    // S22 — lanes (e4,k16)
    float acc[25];
    #pragma unroll
    for (int i = 0; i < 25; ++i) acc[i] = 0.f;
    for (int base = 0; base < cnt; base += 8) {
      #pragma unroll
      for (int u = 0; u < 2; ++u) {
        int idx = base + 4*u + e4;
        float w = (idx < cnt) ? 1.f : 0.f;
        int ic  = (idx < cnt) ? idx : 0;
        int2 en = eb[ic];
        int e = en.x, n = en.y;
        float s2a[5];
        #pragma unroll
        for (int m = 0; m < 5; ++m) s2a[m] = ldv(sh2, e*5+m);
        float rb2k = ldv(rb2, e*16 + k16) * w;
        float f2k[5];
        #pragma unroll
        for (int b = 0; b < 5; ++b) f2k[b] = ldv(f2, n*80 + b*16 + k16);
        #pragma unroll
        for (int aa = 0; aa < 5; ++aa) {
          float sa = rb2k * s2a[aa];
          #pragma unroll
          for (int b = 0; b < 5; ++b)
            acc[aa*5+b] = fmaf(sa, f2k[b], acc[aa*5+b]);
        }
      }
    }
    #pragma unroll
    for (int i = 0; i < 25; ++i) {
      acc[i] += __shfl_xor(acc[i], 16);
      acc[i] += __shfl_xor(acc[i], 32);
    }
    const float* C220 = cgf + 390;
    const float* C221 = cgf + 415;
    const float* C222 = cgf + 490;
    float x220, x221[3], x222[5];
    {
      float t = 0.f;
      #pragma unroll
      for (int q = 0; q < 25; ++q) t = fmaf(acc[q], C220[q], t);
      x220 = t;
    }
    #pragma unroll
    for (int M = 0; M < 3; ++M) {
      float t = 0.f;
      #pragma unroll
      for (int q = 0; q < 25; ++q) t = fmaf(acc[q], C221[q*3+M], t);
      x221[M] = t;
    }
    #pragma unroll
    for (int M = 0; M < 5; ++M) {
      float t = 0.f;
      #pragma unroll
      for (int q = 0; q < 25; ++q) t = fmaf(acc[q], C222[q*5+M], t);
      x222[M] = t;
    }
    if (lane < 16) {
      xg[56+k16] = x220;
      #pragma unroll
      for (int M = 0; M < 3; ++M) xg[312+M*40+24+k16] = x221[M];
      #pragma unroll
      for (int M = 0; M < 5; ++M) xg[432+M*72+56+k16] = x222[M];
      atomicAdd(&s1r[56+k16], x220*x220);
      atomicAdd(&s1r[176+k16], x221[0]*x221[0]+x221[1]*x221[1]+x221[2]*x221[2]);
      atomicAdd(&s1r[248+k16], x222[0]*x222[0]+x222[1]*x222[1]+x222[2]*x222[2]
                              + x222[3]*x222[3]+x222[4]*x222[4]);
    }
  }
}

// ---------------- monolithic kernel (small-ws fallback only) ---------------
// MODE 1: epilogue A (densities + s1p).  MODE 2: epilogue B (norm + linear).
template<typename T, int MODE>
__global__ __launch_bounds__(256) void k_main(
    const T* __restrict__ rb0, const T* __restrict__ rb1, const T* __restrict__ rb2,
    const T* __restrict__ sh0, const T* __restrict__ sh1, const T* __restrict__ sh2,
    const T* __restrict__ emb, const T* __restrict__ f0, const T* __restrict__ f1,
    const T* __restrict__ f2, const int2* __restrict__ el2,
    const int* __restrict__ offs, const float* __restrict__ cgf,
    float* __restrict__ s1p, const float* __restrict__ inv,
    float* __restrict__ s2p, LinP lp, T* __restrict__ out,
    const int* __restrict__ flag)
{
  if (flag[0] != dtid<T>()) return;
  int lane = threadIdx.x & 63;
  int wv   = threadIdx.x >> 6;
  int tix  = threadIdx.x;
  int a = blockIdx.x;
  int beg = offs[a];
  int cnt = offs[a+1] - beg;
  int k32 = lane & 31, e2 = lane >> 5;
  int k16 = lane & 15, e4 = lane >> 4;
  int ab = a & 63;
  float* s1r = s1p + ab*296;

  __shared__ int2 sel[256];
  __shared__ __align__(16) float L[952];
  __shared__ float red[4][5];

  float acc[25];
  #pragma unroll
  for (int i = 0; i < 25; ++i) acc[i] = 0.f;

  for (int cbase = 0; cbase < cnt; cbase += 256) {
    int nch = cnt - cbase; if (nch > 256) nch = 256;
    __syncthreads();
    if (tix < nch) sel[tix] = el2[beg + cbase + tix];
    __syncthreads();

    if (wv == 0) {
      for (int base = 0; base < nch; base += 4) {
        #pragma unroll
        for (int u = 0; u < 2; ++u) {
          int idx = base + 2*u + e2;
          float w = (idx < nch) ? 1.f : 0.f;
          int ic  = (idx < nch) ? idx : 0;
          int2 en = sel[ic];
          int e = en.x, n = en.y;
          float s0 = ldv(sh0, e);
          float s1a0 = ldv(sh1, e*3+0), s1a1 = ldv(sh1, e*3+1), s1a2 = ldv(sh1, e*3+2);
          float rb0k = ldv(rb0, e*32 + k32) * w;
          float ek   = ldv(emb, n*32 + k32);
          float f0k  = ldv(f0,  n*32 + k32);
          float ve0 = s0 * rb0k;
          acc[0] = fmaf(ve0, ek, acc[0]);
          acc[4] = fmaf(ve0, f0k, acc[4]);
          if (k32 < 24) {
            float rb1k = ldv(rb1, e*24 + k32) * w;
            float f1k0 = ldv(f1, n*72 + k32);
            float f1k1 = ldv(f1, n*72 + 24 + k32);
            float f1k2 = ldv(f1, n*72 + 48 + k32);
            float rbek = rb1k * ek;
            acc[1] = fmaf(s1a0, rbek, acc[1]);
            acc[2] = fmaf(s1a1, rbek, acc[2]);
            acc[3] = fmaf(s1a2, rbek, acc[3]);
            acc[5] = fmaf(ve0, f1k0, acc[5]);
            acc[6] = fmaf(ve0, f1k1, acc[6]);
            acc[7] = fmaf(ve0, f1k2, acc[7]);
            float g3 = rb1k * f0k;
            acc[8]  = fmaf(g3, s1a0, acc[8]);
            acc[9]  = fmaf(g3, s1a1, acc[9]);
            acc[10] = fmaf(g3, s1a2, acc[10]);
            #pragma unroll
            for (int aa = 0; aa < 3; ++aa) {
              float sa = rb1k * ((aa==0)?s1a0:(aa==1)?s1a1:s1a2);
              acc[11+aa*3+0] = fmaf(sa, f1k0, acc[11+aa*3+0]);
              acc[11+aa*3+1] = fmaf(sa, f1k1, acc[11+aa*3+1]);
              acc[11+aa*3+2] = fmaf(sa, f1k2, acc[11+aa*3+2]);
            }
          }
        }
      }
    } else if (wv == 1) {
      for (int base = 0; base < nch; base += 8) {
        #pragma unroll
        for (int u = 0; u < 2; ++u) {
          int idx = base + 4*u + e4;
          float w = (idx < nch) ? 1.f : 0.f;
          int ic  = (idx < nch) ? idx : 0;
          int2 en = sel[ic];
          int e = en.x, n = en.y;
          float s0 = ldv(sh0, e);
          float s1a[3];
          #pragma unroll
          for (int m = 0; m < 3; ++m) s1a[m] = ldv(sh1, e*3+m);
          float s2a[5];
          #pragma unroll
          for (int m = 0; m < 5; ++m) s2a[m] = ldv(sh2, e*5+m);
          float rb0k = ldv(rb0, e*32 + k16) * w;
          float rb1k = ldv(rb1, e*24 + k16) * w;
          float rb2k = ldv(rb2, e*16 + k16) * w;
          float ek   = ldv(emb, n*32 + k16);
          float f2k[5];
          #pragma unroll
          for (int b = 0; b < 5; ++b) f2k[b] = ldv(f2, n*80 + b*16 + k16);
          float re = rb2k * ek;
          #pragma unroll
          for (int m = 0; m < 5; ++m) acc[m] = fmaf(s2a[m], re, acc[m]);
          float ve0 = s0 * rb0k;
          #pragma unroll
          for (int b = 0; b < 5; ++b) acc[5+b] = fmaf(ve0, f2k[b], acc[5+b]);
          #pragma unroll
          for (int aa = 0; aa < 3; ++aa) {
            float sa = rb1k * s1a[aa];
            #pragma unroll
            for (int b = 0; b < 5; ++b)
              acc[10+aa*5+b] = fmaf(sa, f2k[b], acc[10+aa*5+b]);
          }
        }
      }
    } else if (wv == 2) {
      for (int base = 0; base < nch; base += 8) {
        #pragma unroll
        for (int u = 0; u < 2; ++u) {
          int idx = base + 4*u + e4;
          float w = (idx < nch) ? 1.f : 0.f;
          int ic  = (idx < nch) ? idx : 0;
          int2 en = sel[ic];
          int e = en.x, n = en.y;
          float s2a[5];
          #pragma unroll
          for (int m = 0; m < 5; ++m) s2a[m] = ldv(sh2, e*5+m);
          float rb2k = ldv(rb2, e*16 + k16) * w;
          float f0k  = ldv(f0,  n*32 + k16);
          float f1k[3];
          #pragma unroll
          for (int b = 0; b < 3; ++b) f1k[b] = ldv(f1, n*72 + b*24 + k16);
          float g9 = rb2k * f0k;
          #pragma unroll
          for (int aa = 0; aa < 5; ++aa) acc[aa] = fmaf(g9, s2a[aa], acc[aa]);
          #pragma unroll
          for (int aa = 0; aa < 5; ++aa) {
            float sa = rb2k * s2a[aa];
            #pragma unroll
            for (int b = 0; b < 3; ++b)
              acc[5+aa*3+b] = fmaf(sa, f1k[b], acc[5+aa*3+b]);
          }
        }
      }
    } else {
      for (int base = 0; base < nch; base += 8) {
        #pragma unroll
        for (int u = 0; u < 2; ++u) {
          int idx = base + 4*u + e4;
          float w = (idx < nch) ? 1.f : 0.f;
          int ic  = (idx < nch) ? idx : 0;
          int2 en = sel[ic];
          int e = en.x, n = en.y;
          float s2a[5];
          #pragma unroll
          for (int m = 0; m < 5; ++m) s2a[m] = ldv(sh2, e*5+m);
          float rb2k = ldv(rb2, e*16 + k16) * w;
          float f2k[5];
          #pragma unroll
          for (int b = 0; b < 5; ++b) f2k[b] = ldv(f2, n*80 + b*16 + k16);
          #pragma unroll
          for (int aa = 0; aa < 5; ++aa) {
            float sa = rb2k * s2a[aa];
            #pragma unroll
            for (int b = 0; b < 5; ++b)
              acc[aa*5+b] = fmaf(sa, f2k[b], acc[aa*5+b]);
          }
        }
      }
    }
  }

  // ---- cross-lane reductions + per-atom cg contraction ----
  if (wv == 0) {
    #pragma unroll
    for (int i = 0; i < 20; ++i) acc[i] += __shfl_xor(acc[i], 32);
    const float* C000 = cgf + 0;
    const float* C011 = cgf + 1;
    const float* C101 = cgf + 35;
    const float* C110 = cgf + 44;
    const float* C111 = cgf + 53;
    const float* C112 = cgf + 80;
    float r[16];
    r[0] = C000[0] * acc[4];
    #pragma unroll
    for (int M = 0; M < 3; ++M) {
      float t = 0.f;
      #pragma unroll
      for (int b = 0; b < 3; ++b) t = fmaf(acc[5+b], C011[b*3+M], t);
      r[1+M] = t;
    }
    #pragma unroll
    for (int M = 0; M < 3; ++M) {
      float t = 0.f;
      #pragma unroll
      for (int aa = 0; aa < 3; ++aa) t = fmaf(acc[8+aa], C101[aa*3+M], t);
      r[4+M] = t;
    }
    {
      float t = 0.f;
      #pragma unroll
      for (int q = 0; q < 9; ++q) t = fmaf(acc[11+q], C110[q], t);
      r[7] = t;
    }
    #pragma unroll
    for (int M = 0; M < 3; ++M) {
      float t = 0.f;
      #pragma unroll
      for (int q = 0; q < 9; ++q) t = fmaf(acc[11+q], C111[q*3+M], t);
      r[8+M] = t;
    }
    #pragma unroll
    for (int M = 0; M < 5; ++M) {
      float t = 0.f;
      #pragma unroll
      for (int q = 0; q < 9; ++q) t = fmaf(acc[11+q], C112[q*5+M], t);
      r[11+M] = t;
    }
    acc[4] = r[0];
    #pragma unroll
    for (int M = 0; M < 3; ++M) acc[5+M]  = r[1+M];
    #pragma unroll
    for (int M = 0; M < 3; ++M) acc[8+M]  = r[4+M];
    acc[11] = r[7];
    #pragma unroll
    for (int M = 0; M < 3; ++M) acc[12+M] = r[8+M];
    #pragma unroll
    for (int M = 0; M < 5; ++M) acc[15+M] = r[11+M];
  } else if (wv == 1) {
    #pragma unroll
    for (int i = 0; i < 25; ++i) {
      acc[i] += __shfl_xor(acc[i], 16);
      acc[i] += __shfl_xor(acc[i], 32);
    }
    const float* C022 = cgf + 10;
    const float* C121 = cgf + 125;
    const float* C122 = cgf + 170;
    float r[13];
    #pragma unroll
    for (int M = 0; M < 5; ++M) {
      float t = 0.f;
      #pragma unroll
      for (int b = 0; b < 5; ++b) t = fmaf(acc[5+b], C022[b*5+M], t);
      r[M] = t;
    }
    #pragma unroll
    for (int M = 0; M < 3; ++M) {
      float t = 0.f;
      #pragma unroll
      for (int q = 0; q < 15; ++q) t = fmaf(acc[10+q], C121[q*3+M], t);
      r[5+M] = t;
    }
    #pragma unroll
    for (int M = 0; M < 5; ++M) {
      float t = 0.f;
      #pragma unroll
      for (int q = 0; q < 15; ++q) t = fmaf(acc[10+q], C122[q*5+M], t);
      r[8+M] = t;
    }
    #pragma unroll
    for (int M = 0; M < 5; ++M) acc[5+M]  = r[M];
    #pragma unroll
    for (int M = 0; M < 3; ++M) acc[10+M] = r[5+M];
    #pragma unroll
    for (int M = 0; M < 5; ++M) acc[13+M] = r[8+M];
  } else if (wv == 2) {
    #pragma unroll
    for (int i = 0; i < 20; ++i) {
      acc[i] += __shfl_xor(acc[i], 16);
      acc[i] += __shfl_xor(acc[i], 32);
    }
    const float* C202 = cgf + 245;
    const float* C211 = cgf + 270;
    const float* C212 = cgf + 315;
    float r[13];
    #pragma unroll
    for (int M = 0; M < 5; ++M) {
      float t = 0.f;
      #pragma unroll
      for (int aa = 0; aa < 5; ++aa) t = fmaf(acc[aa], C202[aa*5+M], t);
      r[M] = t;
    }
    #pragma unroll
    for (int M = 0; M < 3; ++M) {
      float t = 0.f;
      #pragma unroll
      for (int q = 0; q < 15; ++q) t = fmaf(acc[5+q], C211[q*3+M], t);
      r[5+M] = t;
    }
    #pragma unroll
    for (int M = 0; M < 5; ++M) {
      float t = 0.f;
      #pragma unroll
      for (int q = 0; q < 15; ++q) t = fmaf(acc[5+q], C212[q*5+M], t);
      r[8+M] = t;
    }
    #pragma unroll
    for (int M = 0; M < 5; ++M) acc[M]   = r[M];
    #pragma unroll
    for (int M = 0; M < 3; ++M) acc[5+M] = r[5+M];
    #pragma unroll
    for (int M = 0; M < 5; ++M) acc[8+M] = r[8+M];
  } else {
    #pragma unroll
    for (int i = 0; i < 25; ++i) {
      acc[i] += __shfl_xor(acc[i], 16);
      acc[i] += __shfl_xor(acc[i], 32);
    }
    const float* C220 = cgf + 390;
    const float* C221 = cgf + 415;
    const float* C222 = cgf + 490;
    float r[9];
    {
      float t = 0.f;
      #pragma unroll
      for (int q = 0; q < 25; ++q) t = fmaf(acc[q], C220[q], t);
      r[0] = t;
    }
    #pragma unroll
    for (int M = 0; M < 3; ++M) {
      float t = 0.f;
      #pragma unroll
      for (int q = 0; q < 25; ++q) t = fmaf(acc[q], C221[q*3+M], t);
      r[1+M] = t;
    }
    #pragma unroll
    for (int M = 0; M < 5; ++M) {
      float t = 0.f;
      #pragma unroll
      for (int q = 0; q < 25; ++q) t = fmaf(acc[q], C222[q*5+M], t);
      r[4+M] = t;
    }
    #pragma unroll
    for (int i = 0; i < 9; ++i) acc[i] = r[i];
  }

  // ---------------- epilogues ----------------
  if constexpr (MODE == 1) {
    if (wv == 0) {
      if (lane < 32) {
        stv(out, O0 + a*32 + k32, acc[0]);
        atomicAdd(&s1r[k32], acc[4]*acc[4]);
        if (k32 < 24) {
          #pragma unroll
          for (int m = 0; m < 3; ++m) stv(out, O1 + a*72 + m*24 + k32, acc[1+m]);
          atomicAdd(&s1r[32+k32], acc[11]*acc[11]);
          float q;
          q = acc[5]*acc[5]+acc[6]*acc[6]+acc[7]*acc[7];
          atomicAdd(&s1r[72+k32], q);
          q = acc[8]*acc[8]+acc[9]*acc[9]+acc[10]*acc[10];
          atomicAdd(&s1r[96+k32], q);
          q = acc[12]*acc[12]+acc[13]*acc[13]+acc[14]*acc[14];
          atomicAdd(&s1r[152+k32], q);
          q = acc[15]*acc[15]+acc[16]*acc[16]+acc[17]*acc[17]
            + acc[18]*acc[18]+acc[19]*acc[19];
          atomicAdd(&s1r[208+k32], q);
        }
      }
    } else if (wv == 1) {
      if (lane < 16) {
        #pragma unroll
        for (int m = 0; m < 5; ++m) stv(out, O2 + a*80 + m*16 + k16, acc[m]);
        float q;
        q = acc[5]*acc[5]+acc[6]*acc[6]+acc[7]*acc[7]+acc[8]*acc[8]+acc[9]*acc[9];
        atomicAdd(&s1r[192+k16], q);
        q = acc[10]*acc[10]+acc[11]*acc[11]+acc[12]*acc[12];
        atomicAdd(&s1r[120+k16], q);
        q = acc[13]*acc[13]+acc[14]*acc[14]+acc[15]*acc[15]
          + acc[16]*acc[16]+acc[17]*acc[17];
        atomicAdd(&s1r[264+k16], q);
      }
    } else if (wv == 2) {
      if (lane < 16) {
        float q;
        q = acc[0]*acc[0]+acc[1]*acc[1]+acc[2]*acc[2]+acc[3]*acc[3]+acc[4]*acc[4];
        atomicAdd(&s1r[232+k16], q);
        q = acc[5]*acc[5]+acc[6]*acc[6]+acc[7]*acc[7];
        atomicAdd(&s1r[136+k16], q);
        q = acc[8]*acc[8]+acc[9]*acc[9]+acc[10]*acc[10]
          + acc[11]*acc[11]+acc[12]*acc[12];
        atomicAdd(&s1r[280+k16], q);
      }
    } else {
      if (lane < 16) {
        atomicAdd(&s1r[56+k16], acc[0]*acc[0]);
        float q;
        q = acc[1]*acc[1]+acc[2]*acc[2]+acc[3]*acc[3];
        atomicAdd(&s1r[176+k16], q);
        q = acc[4]*acc[4]+acc[5]*acc[5]+acc[6]*acc[6]
          + acc[7]*acc[7]+acc[8]*acc[8];
        atomicAdd(&s1r[248+k16], q);
      }
    }
  }

  if constexpr (MODE == 2) {
    if (wv == 0) {
      if (lane < 32) {
        L[k32] = acc[4]*inv[k32];
        if (k32 < 24) {
          L[32+k32] = acc[11]*inv[32+k32];
          #pragma unroll
          for (int M = 0; M < 3; ++M) L[72+M*80+k32]     = acc[5+M]*inv[72+k32];
          #pragma unroll
          for (int M = 0; M < 3; ++M) L[72+M*80+24+k32]  = acc[8+M]*inv[96+k32];
          #pragma unroll
          for (int M = 0; M < 3; ++M) L[312+M*40+k32]    = acc[12+M]*inv[152+k32];
          #pragma unroll
          for (int M = 0; M < 5; ++M) L[432+M*72+16+k32] = acc[15+M]*inv[208+k32];
        }
      }
    } else if (wv == 1) {
      if (lane < 16) {
        #pragma unroll
        for (int M = 0; M < 5; ++M) L[432+M*72+k16]    = acc[5+M]*inv[192+k16];
        #pragma unroll
        for (int M = 0; M < 3; ++M) L[72+M*80+48+k16]  = acc[10+M]*inv[120+k16];
        #pragma unroll
        for (int M = 0; M < 5; ++M) L[792+M*32+k16]    = acc[13+M]*inv[264+k16];
      }
    } else if (wv == 2) {
      if (lane < 16) {
        #pragma unroll
        for (int M = 0; M < 5; ++M) L[432+M*72+40+k16] = acc[0+M]*inv[232+k16];
        #pragma unroll
        for (int M = 0; M < 3; ++M) L[72+M*80+64+k16]  = acc[5+M]*inv[136+k16];
        #pragma unroll
        for (int M = 0; M < 5; ++M) L[792+M*32+16+k16] = acc[8+M]*inv[280+k16];
      }
    } else {
      if (lane < 16) {
        L[56+k16] = acc[0]*inv[56+k16];
        #pragma unroll
        for (int M = 0; M < 3; ++M) L[312+M*40+24+k16] = acc[1+M]*inv[176+k16];
        #pragma unroll
        for (int M = 0; M < 5; ++M) L[432+M*72+56+k16] = acc[4+M]*inv[248+k16];
      }
    }
    __syncthreads();
    int t = threadIdx.x;
    float y2[5] = {0.f,0.f,0.f,0.f,0.f};
    for (int tau = t; tau < 336; tau += 256) {
      int ls = 0;
      while (tau >= c_cum[ls+1]) ++ls;
      int rem = tau - c_cum[ls];
      int kn = c_kout[ls], fin = c_fin[ls];
      int M = rem / kn, ko = rem - M*kn;
      const T* W = (const T*)lp.W[ls];
      float y = ldv((const T*)lp.B[ls], ko);
      const float* xv = &L[c_xb[ls] + M*fin];
      for (int f = 0; f < fin; ++f) y = fmaf(xv[f], ldv(W, f*kn+ko), y);
      stv(out, c_yoff[ls] + (a*c_Ms[ls] + M)*kn + ko, y);
      y2[ls] += y*y;
    }
    #pragma unroll
    for (int i = 0; i < 5; ++i) {
      y2[i] += __shfl_xor(y2[i], 1);  y2[i] += __shfl_xor(y2[i], 2);
      y2[i] += __shfl_xor(y2[i], 4);  y2[i] += __shfl_xor(y2[i], 8);
      y2[i] += __shfl_xor(y2[i], 16); y2[i] += __shfl_xor(y2[i], 32);
    }
    if (lane == 0) {
      #pragma unroll
      for (int i = 0; i < 5; ++i) red[wv][i] = y2[i];
    }
    __syncthreads();
    if (t == 0) {
      #pragma unroll
      for (int i = 0; i < 5; ++i)
        atomicAdd(&s2p[i*64 + ab], red[0][i]+red[1][i]+red[2][i]+red[3][i]);
    }
  }
}

// ---------------- big path: normalize + linear from stored x ----------------
template<typename T>
__global__ __launch_bounds__(256) void k_lin(
    const float* __restrict__ xg, const float* __restrict__ inv,
    LinP lp, T* __restrict__ out, float* __restrict__ s2p,
    const int* __restrict__ flag)
{
  if (flag[0] != dtid<T>()) return;
  int a = blockIdx.x;
  int t = threadIdx.x;
  __shared__ float L[952];
  for (int i = t; i < 952; i += 256) {
    int ch;
    if      (i < 72)  ch = i;
    else if (i < 312) ch = 72  + (i-72)  % 80;
    else if (i < 432) ch = 152 + (i-312) % 40;
    else if (i < 792) ch = 192 + (i-432) % 72;
    else              ch = 264 + (i-792) % 32;
    L[i] = xg[a*952 + i] * inv[ch];
  }
  __syncthreads();
  float y2[5] = {0.f,0.f,0.f,0.f,0.f};
  for (int tau = t; tau < 336; tau += 256) {
    int ls = 0;
    while (tau >= c_cum[ls+1]) ++ls;
    int rem = tau - c_cum[ls];
    int kn = c_kout[ls], fin = c_fin[ls];
    int M = rem / kn, ko = rem - M*kn;
    const T* W = (const T*)lp.W[ls];
    float y = ldv((const T*)lp.B[ls], ko);
    const float* xv = &L[c_xb[ls] + M*fin];
    for (int f = 0; f < fin; ++f) y = fmaf(xv[f], ldv(W, f*kn+ko), y);
    stv(out, c_yoff[ls] + (a*c_Ms[ls] + M)*kn + ko, y);
    y2[ls] += y*y;
  }
  __shared__ float red[4][5];
  #pragma unroll
  for (int i = 0; i < 5; ++i) {
    y2[i] += __shfl_xor(y2[i], 1);  y2[i] += __shfl_xor(y2[i], 2);
    y2[i] += __shfl_xor(y2[i], 4);  y2[i] += __shfl_xor(y2[i], 8);
    y2[i] += __shfl_xor(y2[i], 16); y2[i] += __shfl_xor(y2[i], 32);
  }
  if ((t & 63) == 0) {
    #pragma unroll
    for (int i = 0; i < 5; ++i) red[t>>6][i] = y2[i];
  }
  __syncthreads();
  if (t == 0) {
    #pragma unroll
    for (int i = 0; i < 5; ++i)
      atomicAdd(&s2p[i*64 + (a & 63)], red[0][i]+red[1][i]+red[2][i]+red[3][i]);
  }
}

// ---------------- reducers ----------------
__global__ void k_red1(const float* __restrict__ s1p, float* __restrict__ inv) {
  int ch = blockIdx.x, lane = threadIdx.x;
  float v = s1p[lane*296 + ch];
  v += __shfl_xor(v, 1);  v += __shfl_xor(v, 2);  v += __shfl_xor(v, 4);
  v += __shfl_xor(v, 8);  v += __shfl_xor(v, 16); v += __shfl_xor(v, 32);
  if (lane == 0) {
    float rows = (ch < 72) ? 10000.f : (ch < 192) ? 30000.f : 50000.f;
    inv[ch] = rsqrtf(v/rows + 1e-12f);
  }
}

__global__ void k_red2(const float* __restrict__ s2p, float* __restrict__ ws2) {
  int ls = blockIdx.x, lane = threadIdx.x;
  float v = s2p[ls*64 + lane];
  v += __shfl_xor(v, 1);  v += __shfl_xor(v, 2);  v += __shfl_xor(v, 4);
  v += __shfl_xor(v, 8);  v += __shfl_xor(v, 16); v += __shfl_xor(v, 32);
  if (lane == 0) ws2[ls] = v;
}

// ---------------- final global RMS scale, in place ----------------
template<typename T>
__global__ void k_scale(const float* __restrict__ ws2, T* __restrict__ out,
                        const int* __restrict__ flag) {
  if (flag[0] != dtid<T>()) return;
  int i = blockIdx.x*blockDim.x + threadIdx.x;
  if (i >= 3360000) return;
  int ls = (i < 320000) ? 0 : (i < 1040000) ? 1 : (i < 1760000) ? 2 : (i < 2560000) ? 3 : 4;
  float scale = rsqrtf(ws2[ls] / (float)c_numel[ls] + 1e-12f);
  stv(out, OY + i, ldv((const T*)out, OY + i) * scale);
}

template<typename T>
static void launch_chain(void* const* d_in, T* out, float* wsf, int* wsi,
                         Ptrs15 cg, LinP lp, bool big, hipStream_t stream) {
  const T* rb0 = (const T*)d_in[0];
  const T* rb1 = (const T*)d_in[1];
  const T* rb2 = (const T*)d_in[2];
  const T* sh0 = (const T*)d_in[3];
  const T* sh1 = (const T*)d_in[4];
  const T* sh2 = (const T*)d_in[5];
  const T* emb = (const T*)d_in[6];
  const T* f0  = (const T*)d_in[7];
  const T* f1  = (const T*)d_in[8];
  const T* f2  = (const T*)d_in[9];
  const int* flag = wsi + IFLAG;
  const int2* el2 = (const int2*)(wsi + IELIST);

  k_cg<T><<<3, 256, 0, stream>>>(cg, wsf, flag);
  if (big) {
    k_role<T><<<25000, 128, 0, stream>>>(rb0, rb1, rb2, sh0, sh1, sh2, emb, f0, f1, f2,
        el2, wsi+IOFFS, wsf+SCG, wsf+SS1P, wsf+SXACC, out, flag);
    k_red1<<<296, 64, 0, stream>>>(wsf+SS1P, wsf+SINV);
    k_lin<T><<<N_ATOMS, 256, 0, stream>>>(wsf+SXACC, wsf+SINV, lp, out, wsf+SS2P, flag);
  } else {
    k_main<T,1><<<N_ATOMS, 256, 0, stream>>>(rb0, rb1, rb2, sh0, sh1, sh2, emb, f0, f1, f2,
        el2, wsi+IOFFS, wsf+SCG, wsf+SS1P, nullptr, nullptr, lp, out, flag);
    k_red1<<<296, 64, 0, stream>>>(wsf+SS1P, wsf+SINV);
    k_main<T,2><<<N_ATOMS, 256, 0, stream>>>(rb0, rb1, rb2, sh0, sh1, sh2, emb, f0, f1, f2,
        el2, wsi+IOFFS, wsf+SCG, nullptr, wsf+SINV, wsf+SS2P, lp, out, flag);
  }
  k_red2<<<5, 64, 0, stream>>>(wsf+SS2P, wsf+SWS2);
  k_scale<T><<<(3360000+255)/256, 256, 0, stream>>>(wsf+SWS2, out, flag);
}

extern "C" void kernel_launch(void* const* d_in, const int* in_sizes, int n_in,
                              void* d_out, int out_size, void* d_ws, size_t ws_size,
                              hipStream_t stream) {
  float* wsf = (float*)d_ws;
  int*   wsi = (int*)(wsf + SINTS);
  const int* centers   = (const int*)d_in[35];
  const int* neighbors = (const int*)d_in[36];
  bool big = ws_size >= (size_t)BIG_FLOATS * 4;

  // Host-side dtype detection.
  // know: 0 = bf16 only, 1 = fp32 only, -1 = ambiguous -> dual chain + probe.
  int know = -1;
  if (in_sizes) {
    long long nb = (long long)in_sizes[0];         // rb0: 200000*32 elems
    if (nb == (long long)N_EDGES*32*2) know = 0;
    else if (nb == (long long)N_EDGES*32*4) know = 1;
  }
  if (know < 0) {
    long long ob = (long long)out_size;            // 5.2M output elems
    if (ob == (long long)OUT_ELEMS*2) know = 0;
    else if (ob == (long long)OUT_ELEMS*4) know = 1;
  }

  Ptrs15 cg;
  for (int i = 0; i < 15; ++i) cg.p[i] = d_in[10+i];
  LinP lp;
  lp.W[0] = d_in[25]; lp.B[0] = d_in[26];
  lp.W[1] = d_in[27]; lp.B[1] = d_in[28];
  lp.W[2] = d_in[29]; lp.B[2] = d_in[30];
  lp.W[3] = d_in[31]; lp.B[3] = d_in[32];
  lp.W[4] = d_in[33]; lp.B[4] = d_in[34];

  k_zero<<<154, 256, 0, stream>>>(wsf, wsi,
                                  (const unsigned short*)d_in[0],
                                  (const unsigned short*)d_in[6]);
  k_hist<<<(N_EDGES+255)/256, 256, 0, stream>>>(centers, wsi+ICOUNT);
  k_scan<<<1, 1024, 0, stream>>>(wsi+ICOUNT, wsi+IOFFS);
  k_scatter2<<<(N_EDGES+255)/256, 256, 0, stream>>>(centers, neighbors, wsi+IOFFS,
                                                    wsi+ICURS, (int2*)(wsi+IELIST));

  if (know != 1) launch_chain<bf16 >(d_in, (bf16*)d_out,  wsf, wsi, cg, lp, big, stream);
  if (know != 0) launch_chain<float>(d_in, (float*)d_out, wsf, wsi, cg, lp, big, stream);
}